// Round 2
// baseline (2238.143 us; speedup 1.0000x reference)
//
#include <hip/hip_runtime.h>
#include <hip/hip_bf16.h>
#include <math.h>

constexpr int T_ = 1024;
constexpr int HDIM = 2048;
constexpr int NH = 16;
constexpr int QKD = 96;   // NOPE+ROPE
constexpr int VD = 64;
constexpr int NEX = 8;
constexpr int MAXTILES = 40;
constexpr float EPSF = 1e-6f;

// ---------------- workspace layout (offsets in floats) ----------------
constexpr size_t OF_CAT  = 0;                           // T*4096 cat_in; later gather (2048x2048)
constexpr size_t OF_X0   = OF_CAT + (size_t)T_ * 4096;  // T*2048 resid
constexpr size_t OF_H    = OF_X0  + (size_t)T_ * 2048;  // T*2048 h, later h2
constexpr size_t OF_QA   = OF_H   + (size_t)T_ * 2048;  // T*512  qa (normed); later SG/SU
constexpr size_t OF_Q    = OF_QA  + (size_t)T_ * 512;   // T*1536 q_a raw, then q
constexpr size_t OF_KVA  = OF_Q   + (size_t)T_ * 1536;  // T*288
constexpr size_t OF_KVCN = OF_KVA + (size_t)T_ * 288;   // T*256
constexpr size_t OF_KV   = OF_KVCN+ (size_t)T_ * 256;   // T*2048; later SHO
constexpr size_t OF_QF   = OF_KV  + (size_t)T_ * 2048;  // T*1536; later MD start
constexpr size_t OF_KF   = OF_QF  + (size_t)T_ * 1536;  // T*1536
constexpr size_t OF_VB   = OF_KF  + (size_t)T_ * 1536;  // T*1024
constexpr size_t OF_OB   = OF_VB  + (size_t)T_ * 1024;  // T*1024
constexpr size_t OF_ATT  = OF_OB  + (size_t)T_ * 1024;  // T*2048
constexpr size_t OF_MG   = OF_ATT + (size_t)T_ * 2048;  // 2048*1024
constexpr size_t OF_MU   = OF_MG  + (size_t)2048 * 1024;// 2048*1024
constexpr size_t OF_ROUT = OF_MU  + (size_t)2048 * 1024;
// aliases (lifetime-disjoint)
constexpr size_t OF_GATH = OF_CAT;                      // 2048x2048 gathered h2 rows
constexpr size_t OF_MD   = OF_QF;                       // 2048x2048 (spans QF+KF+VB)
constexpr size_t OF_SG   = OF_QA;                       // T*1024
constexpr size_t OF_SU   = OF_QA + (size_t)T_ * 1024;   // T*1024
constexpr size_t OF_SHO  = OF_KV;                       // T*2048

// ---------------- block reductions ----------------
__device__ __forceinline__ float block_sum(float v) {
    __shared__ float sbuf[9];
    int lane = threadIdx.x & 63;
    int wid  = threadIdx.x >> 6;
#pragma unroll
    for (int off = 32; off > 0; off >>= 1) v += __shfl_down(v, off);
    __syncthreads();
    if (lane == 0) sbuf[wid] = v;
    __syncthreads();
    if (threadIdx.x == 0) {
        float s = 0.f;
        int nw = blockDim.x >> 6;
        for (int i = 0; i < nw; i++) s += sbuf[i];
        sbuf[8] = s;
    }
    __syncthreads();
    return sbuf[8];
}

__device__ __forceinline__ float block_max(float v) {
    __shared__ float mbuf[9];
    int lane = threadIdx.x & 63;
    int wid  = threadIdx.x >> 6;
#pragma unroll
    for (int off = 32; off > 0; off >>= 1) v = fmaxf(v, __shfl_down(v, off));
    __syncthreads();
    if (lane == 0) mbuf[wid] = v;
    __syncthreads();
    if (threadIdx.x == 0) {
        float s = -1e30f;
        int nw = blockDim.x >> 6;
        for (int i = 0; i < nw; i++) s = fmaxf(s, mbuf[i]);
        mbuf[8] = s;
    }
    __syncthreads();
    return mbuf[8];
}

// ---------------- embedding + rmsnorm + concat ----------------
__global__ void embed_cat_kernel(const int* __restrict__ ids, const float* __restrict__ embed,
                                 const float* __restrict__ enorm, const float* __restrict__ prev,
                                 const float* __restrict__ hnorm, float* __restrict__ cat) {
    int t = blockIdx.x;
    const float* e = embed + (size_t)ids[t] * HDIM;
    float ss = 0.f;
    for (int i = threadIdx.x; i < HDIM; i += blockDim.x) { float v = e[i]; ss += v * v; }
    float r = rsqrtf(block_sum(ss) / HDIM + EPSF);
    for (int i = threadIdx.x; i < HDIM; i += blockDim.x)
        cat[(size_t)t * 4096 + i] = e[i] * r * enorm[i];
    const float* p = prev + (size_t)t * HDIM;
    ss = 0.f;
    for (int i = threadIdx.x; i < HDIM; i += blockDim.x) { float v = p[i]; ss += v * v; }
    r = rsqrtf(block_sum(ss) / HDIM + EPSF);
    for (int i = threadIdx.x; i < HDIM; i += blockDim.x)
        cat[(size_t)t * 4096 + 2048 + i] = p[i] * r * hnorm[i];
}

// ---------------- generic rmsnorm ----------------
__global__ void rmsnorm_kernel(const float* __restrict__ in, int in_stride, int width,
                               const float* __restrict__ w, float* __restrict__ out, int out_stride) {
    int t = blockIdx.x;
    const float* x = in + (size_t)t * in_stride;
    float ss = 0.f;
    for (int i = threadIdx.x; i < width; i += blockDim.x) { float v = x[i]; ss += v * v; }
    float r = rsqrtf(block_sum(ss) / width + EPSF);
    float* o = out + (size_t)t * out_stride;
    for (int i = threadIdx.x; i < width; i += blockDim.x) o[i] = x[i] * r * w[i];
}

// ---------------- fp32 tiled GEMM: C[M][N] = A[M][K] @ B[K][N] ----------------
__global__ __launch_bounds__(256) void sgemm(const float* __restrict__ A, const float* __restrict__ B,
                                             float* __restrict__ C, int M, int N, int K) {
    alignas(16) __shared__ float As[16][68];
    alignas(16) __shared__ float Bs[16][64];
    const int tid = threadIdx.x;
    const int tx = tid & 15, ty = tid >> 4;
    const int row0 = blockIdx.y * 64, col0 = blockIdx.x * 64;
    const int ar = tid >> 2, ac = (tid & 3) << 2;
    const int br = tid >> 4, bc = (tid & 15) << 2;
    float acc[4][4] = {};
    for (int k0 = 0; k0 < K; k0 += 16) {
        float4 av = *(const float4*)(A + (size_t)(row0 + ar) * K + k0 + ac);
        As[ac + 0][ar] = av.x; As[ac + 1][ar] = av.y; As[ac + 2][ar] = av.z; As[ac + 3][ar] = av.w;
        int gc = col0 + bc;
        float4 bv;
        const float* brow = B + (size_t)(k0 + br) * N;
        if (gc + 3 < N) bv = *(const float4*)(brow + gc);
        else {
            bv.x = (gc + 0 < N) ? brow[gc + 0] : 0.f;
            bv.y = (gc + 1 < N) ? brow[gc + 1] : 0.f;
            bv.z = (gc + 2 < N) ? brow[gc + 2] : 0.f;
            bv.w = (gc + 3 < N) ? brow[gc + 3] : 0.f;
        }
        *(float4*)(&Bs[br][bc]) = bv;
        __syncthreads();
#pragma unroll
        for (int k = 0; k < 16; k++) {
            float4 a = *(const float4*)(&As[k][ty << 2]);
            float4 b = *(const float4*)(&Bs[k][tx << 2]);
            acc[0][0] += a.x * b.x; acc[0][1] += a.x * b.y; acc[0][2] += a.x * b.z; acc[0][3] += a.x * b.w;
            acc[1][0] += a.y * b.x; acc[1][1] += a.y * b.y; acc[1][2] += a.y * b.z; acc[1][3] += a.y * b.w;
            acc[2][0] += a.z * b.x; acc[2][1] += a.z * b.y; acc[2][2] += a.z * b.z; acc[2][3] += a.z * b.w;
            acc[3][0] += a.w * b.x; acc[3][1] += a.w * b.y; acc[3][2] += a.w * b.z; acc[3][3] += a.w * b.w;
        }
        __syncthreads();
    }
#pragma unroll
    for (int i = 0; i < 4; i++) {
        int r = row0 + (ty << 2) + i;
#pragma unroll
        for (int j = 0; j < 4; j++) {
            int c = col0 + (tx << 2) + j;
            if (c < N) C[(size_t)r * N + c] = acc[i][j];
        }
    }
}

// ---------------- MoE grouped GEMM (tile-mapped) ----------------
__global__ __launch_bounds__(256) void moe_gemm(const float* __restrict__ Abase, const float* __restrict__ Wall,
                                                float* __restrict__ Cbase, const int4* __restrict__ tilemap,
                                                int K, int N) {
    int4 tm = tilemap[blockIdx.y];
    int nrows = tm.z;
    if (nrows == 0) return;
    const float* A = Abase + (size_t)tm.y * K;
    float* C = Cbase + (size_t)tm.y * N;
    const float* B = Wall + (size_t)tm.x * K * N;

    alignas(16) __shared__ float As[16][68];
    alignas(16) __shared__ float Bs[16][64];
    const int tid = threadIdx.x;
    const int tx = tid & 15, ty = tid >> 4;
    const int col0 = blockIdx.x * 64;
    const int ar = tid >> 2, ac = (tid & 3) << 2;
    const int br = tid >> 4, bc = (tid & 15) << 2;
    float acc[4][4] = {};
    for (int k0 = 0; k0 < K; k0 += 16) {
        float4 av = make_float4(0.f, 0.f, 0.f, 0.f);
        if (ar < nrows) av = *(const float4*)(A + (size_t)ar * K + k0 + ac);
        As[ac + 0][ar] = av.x; As[ac + 1][ar] = av.y; As[ac + 2][ar] = av.z; As[ac + 3][ar] = av.w;
        float4 bv = *(const float4*)(B + (size_t)(k0 + br) * N + col0 + bc);
        *(float4*)(&Bs[br][bc]) = bv;
        __syncthreads();
#pragma unroll
        for (int k = 0; k < 16; k++) {
            float4 a = *(const float4*)(&As[k][ty << 2]);
            float4 b = *(const float4*)(&Bs[k][tx << 2]);
            acc[0][0] += a.x * b.x; acc[0][1] += a.x * b.y; acc[0][2] += a.x * b.z; acc[0][3] += a.x * b.w;
            acc[1][0] += a.y * b.x; acc[1][1] += a.y * b.y; acc[1][2] += a.y * b.z; acc[1][3] += a.y * b.w;
            acc[2][0] += a.z * b.x; acc[2][1] += a.z * b.y; acc[2][2] += a.z * b.z; acc[2][3] += a.z * b.w;
            acc[3][0] += a.w * b.x; acc[3][1] += a.w * b.y; acc[3][2] += a.w * b.z; acc[3][3] += a.w * b.w;
        }
        __syncthreads();
    }
#pragma unroll
    for (int i = 0; i < 4; i++) {
        int r = (ty << 2) + i;
        if (r < nrows) {
#pragma unroll
            for (int j = 0; j < 4; j++) {
                int c = col0 + (tx << 2) + j;
                if (c < N) C[(size_t)r * N + c] = acc[i][j];
            }
        }
    }
}

// ---------------- RoPE + build qf/kf/v ----------------
__global__ void prep_qkv_kernel(const float* __restrict__ q, const float* __restrict__ kva,
                                const float* __restrict__ kv, const int* __restrict__ positions,
                                float* __restrict__ qf, float* __restrict__ kf, float* __restrict__ vb) {
    int t = blockIdx.x;
    __shared__ float cs[16], sn[16];
    if (threadIdx.x < 16) {
        float invf = powf(10000.f, -(float)(2 * threadIdx.x) / 32.f);
        float fr = (float)positions[t] * invf;
        cs[threadIdx.x] = cosf(fr);
        sn[threadIdx.x] = sinf(fr);
    }
    __syncthreads();
    for (int i = threadIdx.x; i < NH * QKD; i += blockDim.x) {
        int h = i / QKD, d = i % QKD;
        float val;
        if (d < 64) val = q[(size_t)t * 1536 + h * QKD + d];
        else {
            int r = d - 64, pr = r >> 1;
            float x1 = q[(size_t)t * 1536 + h * QKD + 64 + 2 * pr];
            float x2 = q[(size_t)t * 1536 + h * QKD + 64 + 2 * pr + 1];
            val = (r & 1) ? (x1 * sn[pr] + x2 * cs[pr]) : (x1 * cs[pr] - x2 * sn[pr]);
        }
        qf[(size_t)t * 1536 + i] = val;
    }
    for (int i = threadIdx.x; i < NH * QKD; i += blockDim.x) {
        int h = i / QKD, d = i % QKD;
        float val;
        if (d < 64) val = kv[(size_t)t * 2048 + h * 128 + d];
        else {
            int r = d - 64, pr = r >> 1;
            float x1 = kva[(size_t)t * 288 + 256 + 2 * pr];
            float x2 = kva[(size_t)t * 288 + 256 + 2 * pr + 1];
            val = (r & 1) ? (x1 * sn[pr] + x2 * cs[pr]) : (x1 * cs[pr] - x2 * sn[pr]);
        }
        kf[(size_t)t * 1536 + i] = val;
    }
    for (int i = threadIdx.x; i < NH * VD; i += blockDim.x) {
        int h = i / VD, d = i % VD;
        vb[(size_t)t * 1024 + i] = kv[(size_t)t * 2048 + h * 128 + 64 + d];
    }
}

// ---------------- attention (one block per (t, head)) ----------------
__global__ __launch_bounds__(256) void attn_kernel(const float* __restrict__ qf, const float* __restrict__ kf,
                                                   const float* __restrict__ vb, float* __restrict__ ob) {
    int t = blockIdx.x, h = blockIdx.y;
    __shared__ float p[1024];
    alignas(16) __shared__ float qs[QKD];
    for (int i = threadIdx.x; i < QKD; i += blockDim.x) qs[i] = qf[(size_t)t * 1536 + h * QKD + i];
    __syncthreads();
    const float scale = rsqrtf(96.f);
    float lmax = -1e30f;
    for (int s = threadIdx.x; s <= t; s += blockDim.x) {
        const float4* k4 = (const float4*)(kf + (size_t)s * 1536 + h * QKD);
        const float4* q4 = (const float4*)qs;
        float d = 0.f;
#pragma unroll
        for (int j = 0; j < 24; j++) {
            float4 a = q4[j], b = k4[j];
            d += a.x * b.x + a.y * b.y + a.z * b.z + a.w * b.w;
        }
        d *= scale;
        p[s] = d;
        lmax = fmaxf(lmax, d);
    }
    float m = block_max(lmax);
    float lsum = 0.f;
    for (int s = threadIdx.x; s <= t; s += blockDim.x) {
        float e = expf(p[s] - m);
        p[s] = e;
        lsum += e;
    }
    float denom = block_sum(lsum);
    float inv = 1.f / denom;
    for (int v = threadIdx.x; v < VD; v += blockDim.x) {
        float acc = 0.f;
        for (int s = 0; s <= t; s++) acc += p[s] * vb[(size_t)s * 1024 + h * VD + v];
        ob[(size_t)t * 1024 + h * VD + v] = acc * inv;
    }
}

// ---------------- routing: gate logits -> sigmoid -> top2 ----------------
__global__ void routing_kernel(const float* __restrict__ h2, const float* __restrict__ gate_w,
                               const float* __restrict__ gate_bias, int* __restrict__ topidx,
                               float* __restrict__ topw) {
    int t = blockIdx.x;
    float acc[8] = {0.f, 0.f, 0.f, 0.f, 0.f, 0.f, 0.f, 0.f};
    for (int i = threadIdx.x; i < HDIM; i += blockDim.x) {
        float hv = h2[(size_t)t * HDIM + i];
        const float* g = gate_w + (size_t)i * 8;
#pragma unroll
        for (int e = 0; e < 8; e++) acc[e] = fmaf(hv, g[e], acc[e]);
    }
    __shared__ float logits[8];
    for (int e = 0; e < 8; e++) {
        float s = block_sum(acc[e]);
        if (threadIdx.x == 0) logits[e] = s;
    }
    __syncthreads();
    if (threadIdx.x == 0) {
        float sig[8], sc[8];
        for (int e = 0; e < 8; e++) {
            sig[e] = 1.f / (1.f + expf(-logits[e]));
            sc[e] = sig[e] + gate_bias[e];
        }
        int i0 = 0;
        for (int e = 1; e < 8; e++) if (sc[e] > sc[i0]) i0 = e;
        int i1 = -1;
        for (int e = 0; e < 8; e++) if (e != i0 && (i1 < 0 || sc[e] > sc[i1])) i1 = e;
        float w0 = sig[i0], w1 = sig[i1], s = w0 + w1 + 1e-20f;
        topidx[t * 2 + 0] = i0; topidx[t * 2 + 1] = i1;
        topw[t * 2 + 0] = w0 / s; topw[t * 2 + 1] = w1 / s;
    }
}

// ---------------- deterministic counting sort by expert + tile map ----------------
__global__ void sort_kernel(const int* __restrict__ topidx, int* __restrict__ sorted_t,
                            int* __restrict__ slotpos, int4* __restrict__ tilemap) {
    __shared__ int counts[8], offs[9];
    int wid = threadIdx.x >> 6, lane = threadIdx.x & 63;
    int cnt = 0;
    for (int base = 0; base < 2 * T_; base += 64) {
        int e = topidx[base + lane];
        unsigned long long m = __ballot(e == wid);
        cnt += __popcll(m);
    }
    if (lane == 0) counts[wid] = cnt;
    __syncthreads();
    if (threadIdx.x == 0) {
        offs[0] = 0;
        for (int e = 0; e < 8; e++) offs[e + 1] = offs[e] + counts[e];
    }
    __syncthreads();
    int pos = offs[wid];
    for (int base = 0; base < 2 * T_; base += 64) {
        int sl = base + lane;
        int e = topidx[sl];
        bool match = (e == wid);
        unsigned long long m = __ballot(match);
        if (match) {
            int before = __popcll(m & ((1ull << lane) - 1ull));
            int pp = pos + before;
            sorted_t[pp] = sl >> 1;
            slotpos[sl] = pp;
        }
        pos += __popcll(m);
    }
    __syncthreads();
    if (threadIdx.x == 0) {
        int nt = 0;
        for (int e = 0; e < 8; e++) {
            int c = counts[e], o = offs[e];
            for (int r = 0; r < c; r += 64) {
                tilemap[nt] = make_int4(e, o + r, min(64, c - r), 0);
                nt++;
            }
        }
        for (int i = nt; i < MAXTILES; i++) tilemap[i] = make_int4(0, 0, 0, 0);
    }
}

// ---------------- gather rows of h2 per sorted slot ----------------
__global__ void gather_kernel(const float* __restrict__ h2, const int* __restrict__ sorted_t,
                              float* __restrict__ gout) {
    int pp = blockIdx.x;
    int t = sorted_t[pp];
    const float4* src = (const float4*)(h2 + (size_t)t * HDIM);
    float4* dst = (float4*)(gout + (size_t)pp * HDIM);
    for (int i = threadIdx.x; i < HDIM / 4; i += blockDim.x) dst[i] = src[i];
}

// ---------------- elementwise ----------------
__global__ void silu_mul_kernel(float* __restrict__ g, const float* __restrict__ u, int n) {
    int stride = gridDim.x * blockDim.x;
    for (int i = blockIdx.x * blockDim.x + threadIdx.x; i < n; i += stride) {
        float x = g[i];
        g[i] = (x / (1.f + expf(-x))) * u[i];
    }
}

__global__ void add_inplace_kernel(float* __restrict__ x, const float* __restrict__ y, int n) {
    int stride = gridDim.x * blockDim.x;
    for (int i = blockIdx.x * blockDim.x + threadIdx.x; i < n; i += stride) x[i] += y[i];
}

// ---------------- final combine -> f32 out ----------------
__global__ void final_kernel(const float* __restrict__ resid, const float* __restrict__ sho,
                             const float* __restrict__ md, const int* __restrict__ slotpos,
                             const float* __restrict__ topw, float* __restrict__ out) {
    int t = blockIdx.x;
    int p0 = slotpos[t * 2 + 0], p1 = slotpos[t * 2 + 1];
    float w0 = topw[t * 2 + 0] * 2.5f, w1 = topw[t * 2 + 1] * 2.5f;
    for (int c = threadIdx.x; c < HDIM; c += blockDim.x) {
        float v = resid[(size_t)t * HDIM + c] + sho[(size_t)t * HDIM + c]
                + w0 * md[(size_t)p0 * HDIM + c] + w1 * md[(size_t)p1 * HDIM + c];
        out[(size_t)t * HDIM + c] = v;
    }
}

// ---------------- launcher ----------------
extern "C" void kernel_launch(void* const* d_in, const int* in_sizes, int n_in,
                              void* d_out, int out_size, void* d_ws, size_t ws_size,
                              hipStream_t stream) {
    (void)in_sizes; (void)n_in; (void)out_size; (void)ws_size;
    const int*   input_ids = (const int*)d_in[0];
    const int*   positions = (const int*)d_in[1];
    const float* prev      = (const float*)d_in[2];
    const float* embed     = (const float*)d_in[3];
    const float* enorm_w   = (const float*)d_in[4];
    const float* hnorm_w   = (const float*)d_in[5];
    const float* eh_proj_w = (const float*)d_in[6];
    const float* in_ln_w   = (const float*)d_in[7];
    const float* post_ln_w = (const float*)d_in[8];
    const float* q_a_w     = (const float*)d_in[9];
    const float* q_a_ln_w  = (const float*)d_in[10];
    const float* q_b_w     = (const float*)d_in[11];
    const float* kv_a_w    = (const float*)d_in[12];
    const float* kv_a_ln_w = (const float*)d_in[13];
    const float* kv_b_w    = (const float*)d_in[14];
    const float* o_w       = (const float*)d_in[15];
    const float* gate_w    = (const float*)d_in[16];
    const float* gate_bias = (const float*)d_in[17];
    const float* exp_g     = (const float*)d_in[18];
    const float* exp_u     = (const float*)d_in[19];
    const float* exp_d     = (const float*)d_in[20];
    const float* sh_g      = (const float*)d_in[21];
    const float* sh_u      = (const float*)d_in[22];
    const float* sh_d      = (const float*)d_in[23];
    float* out = (float*)d_out;

    float* ws = (float*)d_ws;
    float* cat   = ws + OF_CAT;
    float* x0    = ws + OF_X0;
    float* h     = ws + OF_H;       // h then h2
    float* qa    = ws + OF_QA;
    float* q     = ws + OF_Q;
    float* kva   = ws + OF_KVA;
    float* kvcn  = ws + OF_KVCN;
    float* kv    = ws + OF_KV;
    float* qf    = ws + OF_QF;
    float* kf    = ws + OF_KF;
    float* vb    = ws + OF_VB;
    float* ob    = ws + OF_OB;
    float* att   = ws + OF_ATT;
    float* mg    = ws + OF_MG;
    float* mu    = ws + OF_MU;
    float* gath  = ws + OF_GATH;
    float* md    = ws + OF_MD;
    float* sg    = ws + OF_SG;
    float* su    = ws + OF_SU;
    float* sho   = ws + OF_SHO;
    int*   ri       = (int*)(ws + OF_ROUT);
    int*   topidx   = ri;              // 2048
    int*   sorted_t = ri + 2048;       // 2048
    int*   slotpos  = ri + 4096;       // 2048
    int4*  tilemap  = (int4*)(ri + 6144); // 40 * int4
    float* topw     = (float*)(ri + 6144 + 4 * MAXTILES); // 2048

    dim3 blk(256);

    // 1. embed + rmsnorm + concat
    embed_cat_kernel<<<T_, blk, 0, stream>>>(input_ids, embed, enorm_w, prev, hnorm_w, cat);
    // 2. x0 = cat @ eh_proj  (1024 x 2048 x 4096)
    sgemm<<<dim3(2048 / 64, T_ / 64), blk, 0, stream>>>(cat, eh_proj_w, x0, T_, 2048, 4096);
    // 3. h = rmsnorm(x0)
    rmsnorm_kernel<<<T_, blk, 0, stream>>>(x0, 2048, 2048, in_ln_w, h, 2048);
    // 4. q_a raw = h @ q_a_w -> q buffer, then rmsnorm -> qa
    sgemm<<<dim3(512 / 64, T_ / 64), blk, 0, stream>>>(h, q_a_w, q, T_, 512, 2048);
    rmsnorm_kernel<<<T_, blk, 0, stream>>>(q, 512, 512, q_a_ln_w, qa, 512);
    // 5. q = qa @ q_b_w  (1024 x 1536 x 512)
    sgemm<<<dim3(1536 / 64, T_ / 64), blk, 0, stream>>>(qa, q_b_w, q, T_, 1536, 512);
    // 6. kva = h @ kv_a_w (1024 x 288 x 2048)
    sgemm<<<dim3((288 + 63) / 64, T_ / 64), blk, 0, stream>>>(h, kv_a_w, kva, T_, 288, 2048);
    // 7. kvcn = rmsnorm(kva[:, :256])
    rmsnorm_kernel<<<T_, blk, 0, stream>>>(kva, 288, 256, kv_a_ln_w, kvcn, 256);
    // 8. kv = kvcn @ kv_b_w (1024 x 2048 x 256)
    sgemm<<<dim3(2048 / 64, T_ / 64), blk, 0, stream>>>(kvcn, kv_b_w, kv, T_, 2048, 256);
    // 9. rope + build qf/kf/v
    prep_qkv_kernel<<<T_, blk, 0, stream>>>(q, kva, kv, positions, qf, kf, vb);
    // 10. attention
    attn_kernel<<<dim3(T_, NH), blk, 0, stream>>>(qf, kf, vb, ob);
    // 11. attn_out = ob @ o_w (1024 x 2048 x 1024)
    sgemm<<<dim3(2048 / 64, T_ / 64), blk, 0, stream>>>(ob, o_w, att, T_, 2048, 1024);
    // 12. resid += attn_out
    add_inplace_kernel<<<2048, blk, 0, stream>>>(x0, att, T_ * 2048);
    // 13. h2 = rmsnorm(resid) -> h
    rmsnorm_kernel<<<T_, blk, 0, stream>>>(x0, 2048, 2048, post_ln_w, h, 2048);
    // 14. routing
    routing_kernel<<<T_, blk, 0, stream>>>(h, gate_w, gate_bias, topidx, topw);
    // 15. sort by expert
    sort_kernel<<<1, 512, 0, stream>>>(topidx, sorted_t, slotpos, tilemap);
    // 16. gather h2 rows per slot
    gather_kernel<<<2 * T_, blk, 0, stream>>>(h, sorted_t, gath);
    // 17. MoE gate / up
    moe_gemm<<<dim3(1024 / 64, MAXTILES), blk, 0, stream>>>(gath, exp_g, mg, tilemap, 2048, 1024);
    moe_gemm<<<dim3(1024 / 64, MAXTILES), blk, 0, stream>>>(gath, exp_u, mu, tilemap, 2048, 1024);
    // 18. act = silu(g) * u
    silu_mul_kernel<<<2048, blk, 0, stream>>>(mg, mu, 2048 * 1024);
    // 19. MoE down
    moe_gemm<<<dim3(2048 / 64, MAXTILES), blk, 0, stream>>>(mg, exp_d, md, tilemap, 1024, 2048);
    // 20. shared MLP
    sgemm<<<dim3(1024 / 64, T_ / 64), blk, 0, stream>>>(h, sh_g, sg, T_, 1024, 2048);
    sgemm<<<dim3(1024 / 64, T_ / 64), blk, 0, stream>>>(h, sh_u, su, T_, 1024, 2048);
    silu_mul_kernel<<<1024, blk, 0, stream>>>(sg, su, T_ * 1024);
    sgemm<<<dim3(2048 / 64, T_ / 64), blk, 0, stream>>>(sg, sh_d, sho, T_, 2048, 1024);
    // 21. final combine -> f32
    final_kernel<<<T_, blk, 0, stream>>>(x0, sho, md, slotpos, topw, out);
}

// Round 4
// 1882.332 us; speedup vs baseline: 1.1890x; 1.1890x over previous
//
#include <hip/hip_runtime.h>
#include <hip/hip_bf16.h>
#include <math.h>

constexpr int T_ = 1024;
constexpr int HDIM = 2048;
constexpr int NH = 16;
constexpr int QKD = 96;   // NOPE+ROPE
constexpr int VD = 64;
constexpr int MAXTILES = 24;   // MoE 128-row tiles: sum ceil(c_e/128) <= 8 + 2048/128 = 24
constexpr float EPSF = 1e-6f;

using f32x4 = __attribute__((ext_vector_type(4))) float;
using s16x8 = __attribute__((ext_vector_type(8))) short;
using s16x4 = __attribute__((ext_vector_type(4))) short;

// ---------------- workspace layout (offsets in floats) ----------------
constexpr size_t OF_CAT  = 0;                           // T*4096 cat_in; later gather (2048x2048)
constexpr size_t OF_X0   = OF_CAT + (size_t)T_ * 4096;  // T*2048 resid
constexpr size_t OF_H    = OF_X0  + (size_t)T_ * 2048;  // T*2048 h, later h2
constexpr size_t OF_QA   = OF_H   + (size_t)T_ * 2048;  // T*512  qa (normed); later SG/SU
constexpr size_t OF_Q    = OF_QA  + (size_t)T_ * 512;   // T*1536 q_a raw, then q
constexpr size_t OF_KVA  = OF_Q   + (size_t)T_ * 1536;  // T*288
constexpr size_t OF_KVCN = OF_KVA + (size_t)T_ * 288;   // T*256
constexpr size_t OF_KV   = OF_KVCN+ (size_t)T_ * 256;   // T*2048; later SHO
constexpr size_t OF_QF   = OF_KV  + (size_t)T_ * 2048;  // T*1536; later MD start
constexpr size_t OF_KF   = OF_QF  + (size_t)T_ * 1536;  // T*1536
constexpr size_t OF_VB   = OF_KF  + (size_t)T_ * 1536;  // T*1024
constexpr size_t OF_OB   = OF_VB  + (size_t)T_ * 1024;  // T*1024
constexpr size_t OF_ATT  = OF_OB  + (size_t)T_ * 1024;  // T*2048
constexpr size_t OF_MG   = OF_ATT + (size_t)T_ * 2048;  // 2048*1024
constexpr size_t OF_MU   = OF_MG  + (size_t)2048 * 1024;// 2048*1024
constexpr size_t OF_ROUT = OF_MU  + (size_t)2048 * 1024;
// aliases (lifetime-disjoint)
constexpr size_t OF_GATH = OF_CAT;                      // 2048x2048 gathered h2 rows
constexpr size_t OF_MD   = OF_QF;                       // 2048x2048 (spans QF+KF+VB)
constexpr size_t OF_SG   = OF_QA;                       // T*1024
constexpr size_t OF_SU   = OF_QA + (size_t)T_ * 1024;   // T*1024
constexpr size_t OF_SHO  = OF_KV;                       // T*2048

// ---------------- helpers ----------------
__device__ __forceinline__ short f2bf(float f) {
    union { float f; unsigned u; } x; x.f = f;
    unsigned r = x.u + 0x7fffu + ((x.u >> 16) & 1u);   // RNE
    return (short)(r >> 16);
}
__device__ __forceinline__ float bf2f(short h) {
    union { unsigned u; float f; } x; x.u = ((unsigned)(unsigned short)h) << 16; return x.f;
}

__device__ __forceinline__ float block_sum(float v) {
    __shared__ float sbuf[9];
    int lane = threadIdx.x & 63;
    int wid  = threadIdx.x >> 6;
#pragma unroll
    for (int off = 32; off > 0; off >>= 1) v += __shfl_down(v, off);
    __syncthreads();
    if (lane == 0) sbuf[wid] = v;
    __syncthreads();
    if (threadIdx.x == 0) {
        float s = 0.f;
        int nw = blockDim.x >> 6;
        for (int i = 0; i < nw; i++) s += sbuf[i];
        sbuf[8] = s;
    }
    __syncthreads();
    return sbuf[8];
}

__device__ __forceinline__ float block_max(float v) {
    __shared__ float mbuf[9];
    int lane = threadIdx.x & 63;
    int wid  = threadIdx.x >> 6;
#pragma unroll
    for (int off = 32; off > 0; off >>= 1) v = fmaxf(v, __shfl_down(v, off));
    __syncthreads();
    if (lane == 0) mbuf[wid] = v;
    __syncthreads();
    if (threadIdx.x == 0) {
        float s = -1e30f;
        int nw = blockDim.x >> 6;
        for (int i = 0; i < nw; i++) s = fmaxf(s, mbuf[i]);
        mbuf[8] = s;
    }
    __syncthreads();
    return mbuf[8];
}

// ---------------- embedding + rmsnorm + concat ----------------
__global__ void embed_cat_kernel(const int* __restrict__ ids, const float* __restrict__ embed,
                                 const float* __restrict__ enorm, const float* __restrict__ prev,
                                 const float* __restrict__ hnorm, float* __restrict__ cat) {
    int t = blockIdx.x;
    const float* e = embed + (size_t)ids[t] * HDIM;
    float ss = 0.f;
    for (int i = threadIdx.x; i < HDIM; i += blockDim.x) { float v = e[i]; ss += v * v; }
    float r = rsqrtf(block_sum(ss) / HDIM + EPSF);
    for (int i = threadIdx.x; i < HDIM; i += blockDim.x)
        cat[(size_t)t * 4096 + i] = e[i] * r * enorm[i];
    const float* p = prev + (size_t)t * HDIM;
    ss = 0.f;
    for (int i = threadIdx.x; i < HDIM; i += blockDim.x) { float v = p[i]; ss += v * v; }
    r = rsqrtf(block_sum(ss) / HDIM + EPSF);
    for (int i = threadIdx.x; i < HDIM; i += blockDim.x)
        cat[(size_t)t * 4096 + 2048 + i] = p[i] * r * hnorm[i];
}

// ---------------- generic rmsnorm ----------------
__global__ void rmsnorm_kernel(const float* __restrict__ in, int in_stride, int width,
                               const float* __restrict__ w, float* __restrict__ out, int out_stride) {
    int t = blockIdx.x;
    const float* x = in + (size_t)t * in_stride;
    float ss = 0.f;
    for (int i = threadIdx.x; i < width; i += blockDim.x) { float v = x[i]; ss += v * v; }
    float r = rsqrtf(block_sum(ss) / width + EPSF);
    float* o = out + (size_t)t * out_stride;
    for (int i = threadIdx.x; i < width; i += blockDim.x) o[i] = x[i] * r * w[i];
}

// =====================================================================
// bf16 MFMA GEMM: C[M][N](f32) = A[M][K](f32->bf16) @ B[K][N](f32->bf16)
// BM=128, BN=64, BK=64; 4 waves 2x2; mfma_f32_16x16x32_bf16.
// SPLIT=true: a = hi + lo (two bf16), D = Ah*Bh + Ah*Bl + Al*Bh -> ~fp32
// accuracy (rel err ~1e-5), used for every GEMM feeding the routing logits.
// A staged [128][72] (row-major, +8 pad); B staged transposed [64][72];
// both fragments use the identical k-octet map, so any HW k-permutation
// cancels (needs only: A-row = lane&15, B-col = lane&15, same k-grouping).
// =====================================================================
template<bool SPLIT>
__global__ __launch_bounds__(256) void gemm_bf16(const float* __restrict__ A, const float* __restrict__ B,
                                                 float* __restrict__ C, int M, int N, int K) {
    __shared__ short As[SPLIT ? 2 : 1][128][72];
    __shared__ short Bs[SPLIT ? 2 : 1][64][72];
    const int tid = threadIdx.x;
    const int lane = tid & 63, wid = tid >> 6;
    const int g = lane >> 4, li = lane & 15;
    const int wm = wid >> 1, wn = wid & 1;        // 2x2 wave grid
    const int row0 = blockIdx.y * 128, col0 = blockIdx.x * 64;

    f32x4 acc[4][2];
#pragma unroll
    for (int mi = 0; mi < 4; mi++)
#pragma unroll
        for (int ni = 0; ni < 2; ni++)
#pragma unroll
            for (int r = 0; r < 4; r++) acc[mi][ni][r] = 0.f;

    const int sar = tid >> 3, sak = (tid & 7) << 3;    // A staging: 4 chunks stride 32 rows
    const int skb = (tid >> 4) << 2, snb = (tid & 15) << 2; // B staging

    for (int k0 = 0; k0 < K; k0 += 64) {
        // ---- stage A ----
#pragma unroll
        for (int i = 0; i < 4; i++) {
            int ar = sar + i * 32;
            const float* src = A + (size_t)(row0 + ar) * K + k0 + sak;
            float4 f0 = *(const float4*)src;
            float4 f1 = *(const float4*)(src + 4);
            float vals[8] = {f0.x, f0.y, f0.z, f0.w, f1.x, f1.y, f1.z, f1.w};
            s16x8 vh, vl;
#pragma unroll
            for (int j = 0; j < 8; j++) {
                short hh = f2bf(vals[j]);
                vh[j] = hh;
                if constexpr (SPLIT) vl[j] = f2bf(vals[j] - bf2f(hh));
            }
            *(s16x8*)&As[0][ar][sak] = vh;
            if constexpr (SPLIT) *(s16x8*)&As[1][ar][sak] = vl;
        }
        // ---- stage B transposed ----
        {
            float4 r4[4];
#pragma unroll
            for (int kk = 0; kk < 4; kk++) {
                const float* brow = B + (size_t)(k0 + skb + kk) * N;
                int gn = col0 + snb;
                if (gn + 3 < N) r4[kk] = *(const float4*)(brow + gn);
                else {
                    r4[kk].x = (gn + 0 < N) ? brow[gn + 0] : 0.f;
                    r4[kk].y = (gn + 1 < N) ? brow[gn + 1] : 0.f;
                    r4[kk].z = (gn + 2 < N) ? brow[gn + 2] : 0.f;
                    r4[kk].w = (gn + 3 < N) ? brow[gn + 3] : 0.f;
                }
            }
#pragma unroll
            for (int n = 0; n < 4; n++) {
                s16x4 wh, wl;
#pragma unroll
                for (int kk = 0; kk < 4; kk++) {
                    float f = (&r4[kk].x)[n];
                    short hh = f2bf(f);
                    wh[kk] = hh;
                    if constexpr (SPLIT) wl[kk] = f2bf(f - bf2f(hh));
                }
                *(s16x4*)&Bs[0][snb + n][skb] = wh;
                if constexpr (SPLIT) *(s16x4*)&Bs[1][snb + n][skb] = wl;
            }
        }
        __syncthreads();
        // ---- compute: 2 k-steps of 32 ----
#pragma unroll
        for (int kk = 0; kk < 64; kk += 32) {
            s16x8 ah[4], bh[2];
#pragma unroll
            for (int mi = 0; mi < 4; mi++) ah[mi] = *(const s16x8*)&As[0][wm * 64 + mi * 16 + li][kk + g * 8];
#pragma unroll
            for (int ni = 0; ni < 2; ni++) bh[ni] = *(const s16x8*)&Bs[0][wn * 32 + ni * 16 + li][kk + g * 8];
            if constexpr (SPLIT) {
                s16x8 al[4], bl[2];
#pragma unroll
                for (int mi = 0; mi < 4; mi++) al[mi] = *(const s16x8*)&As[1][wm * 64 + mi * 16 + li][kk + g * 8];
#pragma unroll
                for (int ni = 0; ni < 2; ni++) bl[ni] = *(const s16x8*)&Bs[1][wn * 32 + ni * 16 + li][kk + g * 8];
#pragma unroll
                for (int mi = 0; mi < 4; mi++)
#pragma unroll
                    for (int ni = 0; ni < 2; ni++) {
                        acc[mi][ni] = __builtin_amdgcn_mfma_f32_16x16x32_bf16(ah[mi], bh[ni], acc[mi][ni], 0, 0, 0);
                        acc[mi][ni] = __builtin_amdgcn_mfma_f32_16x16x32_bf16(al[mi], bh[ni], acc[mi][ni], 0, 0, 0);
                        acc[mi][ni] = __builtin_amdgcn_mfma_f32_16x16x32_bf16(ah[mi], bl[ni], acc[mi][ni], 0, 0, 0);
                    }
            } else {
#pragma unroll
                for (int mi = 0; mi < 4; mi++)
#pragma unroll
                    for (int ni = 0; ni < 2; ni++)
                        acc[mi][ni] = __builtin_amdgcn_mfma_f32_16x16x32_bf16(ah[mi], bh[ni], acc[mi][ni], 0, 0, 0);
            }
        }
        __syncthreads();
    }
    // ---- epilogue: C/D map col=lane&15, row=(lane>>4)*4+reg ----
#pragma unroll
    for (int mi = 0; mi < 4; mi++)
#pragma unroll
        for (int ni = 0; ni < 2; ni++) {
            int gc = col0 + wn * 32 + ni * 16 + li;
            if (gc < N) {
#pragma unroll
                for (int r = 0; r < 4; r++) {
                    int gr = row0 + wm * 64 + mi * 16 + g * 4 + r;
                    C[(size_t)gr * N + gc] = acc[mi][ni][r];
                }
            }
        }
}

// ---------------- MoE grouped GEMM, plain bf16 (post-routing) ----------------
__global__ __launch_bounds__(256) void moe_gemm_bf16(const float* __restrict__ Abase, const float* __restrict__ Wall,
                                                     float* __restrict__ Cbase, const int4* __restrict__ tilemap,
                                                     int K, int N) {
    int4 tm = tilemap[blockIdx.y];
    int nrows = tm.z;
    if (nrows == 0) return;
    const float* A = Abase + (size_t)tm.y * K;
    float* C = Cbase + (size_t)tm.y * N;
    const float* B = Wall + (size_t)tm.x * K * N;

    alignas(16) __shared__ short As[128][72];
    alignas(16) __shared__ short Bs[64][72];
    const int tid = threadIdx.x;
    const int lane = tid & 63, wid = tid >> 6;
    const int g = lane >> 4, li = lane & 15;
    const int wm = wid >> 1, wn = wid & 1;
    const int col0 = blockIdx.x * 64;

    f32x4 acc[4][2];
#pragma unroll
    for (int mi = 0; mi < 4; mi++)
#pragma unroll
        for (int ni = 0; ni < 2; ni++)
#pragma unroll
            for (int r = 0; r < 4; r++) acc[mi][ni][r] = 0.f;

    const int sar = tid >> 3, sak = (tid & 7) << 3;
    const int skb = (tid >> 4) << 2, snb = (tid & 15) << 2;

    for (int k0 = 0; k0 < K; k0 += 64) {
#pragma unroll
        for (int i = 0; i < 4; i++) {
            int ar = sar + i * 32;
            s16x8 v;
            if (ar < nrows) {
                const float* src = A + (size_t)ar * K + k0 + sak;
                float4 f0 = *(const float4*)src;
                float4 f1 = *(const float4*)(src + 4);
                v[0] = f2bf(f0.x); v[1] = f2bf(f0.y); v[2] = f2bf(f0.z); v[3] = f2bf(f0.w);
                v[4] = f2bf(f1.x); v[5] = f2bf(f1.y); v[6] = f2bf(f1.z); v[7] = f2bf(f1.w);
            } else {
#pragma unroll
                for (int j = 0; j < 8; j++) v[j] = 0;
            }
            *(s16x8*)&As[ar][sak] = v;
        }
        {
            float4 r4[4];
#pragma unroll
            for (int kk = 0; kk < 4; kk++)
                r4[kk] = *(const float4*)(B + (size_t)(k0 + skb + kk) * N + col0 + snb);
#pragma unroll
            for (int n = 0; n < 4; n++) {
                s16x4 w;
                w[0] = f2bf((&r4[0].x)[n]); w[1] = f2bf((&r4[1].x)[n]);
                w[2] = f2bf((&r4[2].x)[n]); w[3] = f2bf((&r4[3].x)[n]);
                *(s16x4*)&Bs[snb + n][skb] = w;
            }
        }
        __syncthreads();
#pragma unroll
        for (int kk = 0; kk < 64; kk += 32) {
            s16x8 a[4], b[2];
#pragma unroll
            for (int mi = 0; mi < 4; mi++) a[mi] = *(const s16x8*)&As[wm * 64 + mi * 16 + li][kk + g * 8];
#pragma unroll
            for (int ni = 0; ni < 2; ni++) b[ni] = *(const s16x8*)&Bs[wn * 32 + ni * 16 + li][kk + g * 8];
#pragma unroll
            for (int mi = 0; mi < 4; mi++)
#pragma unroll
                for (int ni = 0; ni < 2; ni++)
                    acc[mi][ni] = __builtin_amdgcn_mfma_f32_16x16x32_bf16(a[mi], b[ni], acc[mi][ni], 0, 0, 0);
        }
        __syncthreads();
    }
#pragma unroll
    for (int mi = 0; mi < 4; mi++)
#pragma unroll
        for (int ni = 0; ni < 2; ni++) {
            int gc = col0 + wn * 32 + ni * 16 + li;
#pragma unroll
            for (int r = 0; r < 4; r++) {
                int gr = wm * 64 + mi * 16 + g * 4 + r;
                if (gr < nrows) C[(size_t)gr * N + gc] = acc[mi][ni][r];
            }
        }
}

// ---------------- RoPE + build qf/kf/v ----------------
__global__ void prep_qkv_kernel(const float* __restrict__ q, const float* __restrict__ kva,
                                const float* __restrict__ kv, const int* __restrict__ positions,
                                float* __restrict__ qf, float* __restrict__ kf, float* __restrict__ vb) {
    int t = blockIdx.x;
    __shared__ float cs[16], sn[16];
    if (threadIdx.x < 16) {
        float invf = powf(10000.f, -(float)(2 * threadIdx.x) / 32.f);
        float fr = (float)positions[t] * invf;
        cs[threadIdx.x] = cosf(fr);
        sn[threadIdx.x] = sinf(fr);
    }
    __syncthreads();
    for (int i = threadIdx.x; i < NH * QKD; i += blockDim.x) {
        int h = i / QKD, d = i % QKD;
        float val;
        if (d < 64) val = q[(size_t)t * 1536 + h * QKD + d];
        else {
            int r = d - 64, pr = r >> 1;
            float x1 = q[(size_t)t * 1536 + h * QKD + 64 + 2 * pr];
            float x2 = q[(size_t)t * 1536 + h * QKD + 64 + 2 * pr + 1];
            val = (r & 1) ? (x1 * sn[pr] + x2 * cs[pr]) : (x1 * cs[pr] - x2 * sn[pr]);
        }
        qf[(size_t)t * 1536 + i] = val;
    }
    for (int i = threadIdx.x; i < NH * QKD; i += blockDim.x) {
        int h = i / QKD, d = i % QKD;
        float val;
        if (d < 64) val = kv[(size_t)t * 2048 + h * 128 + d];
        else {
            int r = d - 64, pr = r >> 1;
            float x1 = kva[(size_t)t * 288 + 256 + 2 * pr];
            float x2 = kva[(size_t)t * 288 + 256 + 2 * pr + 1];
            val = (r & 1) ? (x1 * sn[pr] + x2 * cs[pr]) : (x1 * cs[pr] - x2 * sn[pr]);
        }
        kf[(size_t)t * 1536 + i] = val;
    }
    for (int i = threadIdx.x; i < NH * VD; i += blockDim.x) {
        int h = i / VD, d = i % VD;
        vb[(size_t)t * 1024 + i] = kv[(size_t)t * 2048 + h * 128 + 64 + d];
    }
}

// ---------------- attention (one block per (t, head)); PV split over 4 waves ----------------
__global__ __launch_bounds__(256) void attn_kernel(const float* __restrict__ qf, const float* __restrict__ kf,
                                                   const float* __restrict__ vb, float* __restrict__ ob) {
    int t = blockIdx.x, h = blockIdx.y;
    __shared__ float p[1024];
    __shared__ float pacc[4][VD];
    alignas(16) __shared__ float qs[QKD];
    for (int i = threadIdx.x; i < QKD; i += blockDim.x) qs[i] = qf[(size_t)t * 1536 + h * QKD + i];
    __syncthreads();
    const float scale = rsqrtf(96.f);
    float lmax = -1e30f;
    for (int s = threadIdx.x; s <= t; s += blockDim.x) {
        const float4* k4 = (const float4*)(kf + (size_t)s * 1536 + h * QKD);
        const float4* q4 = (const float4*)qs;
        float d = 0.f;
#pragma unroll
        for (int j = 0; j < 24; j++) {
            float4 a = q4[j], b = k4[j];
            d += a.x * b.x + a.y * b.y + a.z * b.z + a.w * b.w;
        }
        d *= scale;
        p[s] = d;
        lmax = fmaxf(lmax, d);
    }
    float m = block_max(lmax);
    float lsum = 0.f;
    for (int s = threadIdx.x; s <= t; s += blockDim.x) {
        float e = expf(p[s] - m);
        p[s] = e;
        lsum += e;
    }
    float denom = block_sum(lsum);
    float inv = 1.f / denom;
    __syncthreads();
    int v = threadIdx.x & 63, sg = threadIdx.x >> 6;
    float acc = 0.f;
    for (int s = sg; s <= t; s += 4) acc += p[s] * vb[(size_t)s * 1024 + h * VD + v];
    pacc[sg][v] = acc;
    __syncthreads();
    if (threadIdx.x < VD)
        ob[(size_t)t * 1024 + h * VD + v] = (pacc[0][v] + pacc[1][v] + pacc[2][v] + pacc[3][v]) * inv;
}

// ---------------- routing: gate logits -> sigmoid -> top2 ----------------
__global__ void routing_kernel(const float* __restrict__ h2, const float* __restrict__ gate_w,
                               const float* __restrict__ gate_bias, int* __restrict__ topidx,
                               float* __restrict__ topw) {
    int t = blockIdx.x;
    float acc[8] = {0.f, 0.f, 0.f, 0.f, 0.f, 0.f, 0.f, 0.f};
    for (int i = threadIdx.x; i < HDIM; i += blockDim.x) {
        float hv = h2[(size_t)t * HDIM + i];
        const float* g = gate_w + (size_t)i * 8;
#pragma unroll
        for (int e = 0; e < 8; e++) acc[e] = fmaf(hv, g[e], acc[e]);
    }
    __shared__ float logits[8];
    for (int e = 0; e < 8; e++) {
        float s = block_sum(acc[e]);
        if (threadIdx.x == 0) logits[e] = s;
    }
    __syncthreads();
    if (threadIdx.x == 0) {
        float sig[8], sc[8];
        for (int e = 0; e < 8; e++) {
            sig[e] = 1.f / (1.f + expf(-logits[e]));
            sc[e] = sig[e] + gate_bias[e];
        }
        int i0 = 0;
        for (int e = 1; e < 8; e++) if (sc[e] > sc[i0]) i0 = e;
        int i1 = -1;
        for (int e = 0; e < 8; e++) if (e != i0 && (i1 < 0 || sc[e] > sc[i1])) i1 = e;
        float w0 = sig[i0], w1 = sig[i1], s = w0 + w1 + 1e-20f;
        topidx[t * 2 + 0] = i0; topidx[t * 2 + 1] = i1;
        topw[t * 2 + 0] = w0 / s; topw[t * 2 + 1] = w1 / s;
    }
}

// ---------------- deterministic counting sort by expert + 128-row tile map ----------------
__global__ void sort_kernel(const int* __restrict__ topidx, int* __restrict__ sorted_t,
                            int* __restrict__ slotpos, int4* __restrict__ tilemap) {
    __shared__ int counts[8], offs[9];
    int wid = threadIdx.x >> 6, lane = threadIdx.x & 63;
    int cnt = 0;
    for (int base = 0; base < 2 * T_; base += 64) {
        int e = topidx[base + lane];
        unsigned long long m = __ballot(e == wid);
        cnt += __popcll(m);
    }
    if (lane == 0) counts[wid] = cnt;
    __syncthreads();
    if (threadIdx.x == 0) {
        offs[0] = 0;
        for (int e = 0; e < 8; e++) offs[e + 1] = offs[e] + counts[e];
    }
    __syncthreads();
    int pos = offs[wid];
    for (int base = 0; base < 2 * T_; base += 64) {
        int sl = base + lane;
        int e = topidx[sl];
        bool match = (e == wid);
        unsigned long long m = __ballot(match);
        if (match) {
            int before = __popcll(m & ((1ull << lane) - 1ull));
            int pp = pos + before;
            sorted_t[pp] = sl >> 1;
            slotpos[sl] = pp;
        }
        pos += __popcll(m);
    }
    __syncthreads();
    if (threadIdx.x == 0) {
        int nt = 0;
        for (int e = 0; e < 8; e++) {
            int c = counts[e], o = offs[e];
            for (int r = 0; r < c; r += 128) {
                tilemap[nt] = make_int4(e, o + r, min(128, c - r), 0);
                nt++;
            }
        }
        for (int i = nt; i < MAXTILES; i++) tilemap[i] = make_int4(0, 0, 0, 0);
    }
}

// ---------------- gather rows of h2 per sorted slot ----------------
__global__ void gather_kernel(const float* __restrict__ h2, const int* __restrict__ sorted_t,
                              float* __restrict__ gout) {
    int pp = blockIdx.x;
    int t = sorted_t[pp];
    const float4* src = (const float4*)(h2 + (size_t)t * HDIM);
    float4* dst = (float4*)(gout + (size_t)pp * HDIM);
    for (int i = threadIdx.x; i < HDIM / 4; i += blockDim.x) dst[i] = src[i];
}

// ---------------- elementwise ----------------
__global__ void silu_mul_kernel(float* __restrict__ g, const float* __restrict__ u, int n) {
    int stride = gridDim.x * blockDim.x;
    for (int i = blockIdx.x * blockDim.x + threadIdx.x; i < n; i += stride) {
        float x = g[i];
        g[i] = (x / (1.f + expf(-x))) * u[i];
    }
}

__global__ void add_inplace_kernel(float* __restrict__ x, const float* __restrict__ y, int n) {
    int stride = gridDim.x * blockDim.x;
    for (int i = blockIdx.x * blockDim.x + threadIdx.x; i < n; i += stride) x[i] += y[i];
}

// ---------------- final combine -> f32 out ----------------
__global__ void final_kernel(const float* __restrict__ resid, const float* __restrict__ sho,
                             const float* __restrict__ md, const int* __restrict__ slotpos,
                             const float* __restrict__ topw, float* __restrict__ out) {
    int t = blockIdx.x;
    int p0 = slotpos[t * 2 + 0], p1 = slotpos[t * 2 + 1];
    float w0 = topw[t * 2 + 0] * 2.5f, w1 = topw[t * 2 + 1] * 2.5f;
    for (int c = threadIdx.x; c < HDIM; c += blockDim.x) {
        float v = resid[(size_t)t * HDIM + c] + sho[(size_t)t * HDIM + c]
                + w0 * md[(size_t)p0 * HDIM + c] + w1 * md[(size_t)p1 * HDIM + c];
        out[(size_t)t * HDIM + c] = v;
    }
}

// ---------------- launcher ----------------
extern "C" void kernel_launch(void* const* d_in, const int* in_sizes, int n_in,
                              void* d_out, int out_size, void* d_ws, size_t ws_size,
                              hipStream_t stream) {
    (void)in_sizes; (void)n_in; (void)out_size; (void)ws_size;
    const int*   input_ids = (const int*)d_in[0];
    const int*   positions = (const int*)d_in[1];
    const float* prev      = (const float*)d_in[2];
    const float* embed     = (const float*)d_in[3];
    const float* enorm_w   = (const float*)d_in[4];
    const float* hnorm_w   = (const float*)d_in[5];
    const float* eh_proj_w = (const float*)d_in[6];
    const float* in_ln_w   = (const float*)d_in[7];
    const float* post_ln_w = (const float*)d_in[8];
    const float* q_a_w     = (const float*)d_in[9];
    const float* q_a_ln_w  = (const float*)d_in[10];
    const float* q_b_w     = (const float*)d_in[11];
    const float* kv_a_w    = (const float*)d_in[12];
    const float* kv_a_ln_w = (const float*)d_in[13];
    const float* kv_b_w    = (const float*)d_in[14];
    const float* o_w       = (const float*)d_in[15];
    const float* gate_w    = (const float*)d_in[16];
    const float* gate_bias = (const float*)d_in[17];
    const float* exp_g     = (const float*)d_in[18];
    const float* exp_u     = (const float*)d_in[19];
    const float* exp_d     = (const float*)d_in[20];
    const float* sh_g      = (const float*)d_in[21];
    const float* sh_u      = (const float*)d_in[22];
    const float* sh_d      = (const float*)d_in[23];
    float* out = (float*)d_out;

    float* ws = (float*)d_ws;
    float* cat   = ws + OF_CAT;
    float* x0    = ws + OF_X0;
    float* h     = ws + OF_H;       // h then h2
    float* qa    = ws + OF_QA;
    float* q     = ws + OF_Q;
    float* kva   = ws + OF_KVA;
    float* kvcn  = ws + OF_KVCN;
    float* kv    = ws + OF_KV;
    float* qf    = ws + OF_QF;
    float* kf    = ws + OF_KF;
    float* vb    = ws + OF_VB;
    float* ob    = ws + OF_OB;
    float* att   = ws + OF_ATT;
    float* mg    = ws + OF_MG;
    float* mu    = ws + OF_MU;
    float* gath  = ws + OF_GATH;
    float* md    = ws + OF_MD;
    float* sg    = ws + OF_SG;
    float* su    = ws + OF_SU;
    float* sho   = ws + OF_SHO;
    int*   ri       = (int*)(ws + OF_ROUT);
    int*   topidx   = ri;              // 2048
    int*   sorted_t = ri + 2048;       // 2048
    int*   slotpos  = ri + 4096;       // 2048
    int4*  tilemap  = (int4*)(ri + 6144); // MAXTILES * int4
    float* topw     = (float*)(ri + 6144 + 4 * MAXTILES); // 2048

    dim3 blk(256);

    // 1. embed + rmsnorm + concat
    embed_cat_kernel<<<T_, blk, 0, stream>>>(input_ids, embed, enorm_w, prev, hnorm_w, cat);
    // 2. x0 = cat @ eh_proj  (1024 x 2048 x 4096)  [split: feeds routing]
    gemm_bf16<true><<<dim3(2048 / 64, T_ / 128), blk, 0, stream>>>(cat, eh_proj_w, x0, T_, 2048, 4096);
    // 3. h = rmsnorm(x0)
    rmsnorm_kernel<<<T_, blk, 0, stream>>>(x0, 2048, 2048, in_ln_w, h, 2048);
    // 4. q_a raw = h @ q_a_w -> q buffer, then rmsnorm -> qa   [split]
    gemm_bf16<true><<<dim3(512 / 64, T_ / 128), blk, 0, stream>>>(h, q_a_w, q, T_, 512, 2048);
    rmsnorm_kernel<<<T_, blk, 0, stream>>>(q, 512, 512, q_a_ln_w, qa, 512);
    // 5. q = qa @ q_b_w  (1024 x 1536 x 512)  [split]
    gemm_bf16<true><<<dim3(1536 / 64, T_ / 128), blk, 0, stream>>>(qa, q_b_w, q, T_, 1536, 512);
    // 6. kva = h @ kv_a_w (1024 x 288 x 2048)  [split]
    gemm_bf16<true><<<dim3(5, T_ / 128), blk, 0, stream>>>(h, kv_a_w, kva, T_, 288, 2048);
    // 7. kvcn = rmsnorm(kva[:, :256])
    rmsnorm_kernel<<<T_, blk, 0, stream>>>(kva, 288, 256, kv_a_ln_w, kvcn, 256);
    // 8. kv = kvcn @ kv_b_w (1024 x 2048 x 256)  [split]
    gemm_bf16<true><<<dim3(2048 / 64, T_ / 128), blk, 0, stream>>>(kvcn, kv_b_w, kv, T_, 2048, 256);
    // 9. rope + build qf/kf/v
    prep_qkv_kernel<<<T_, blk, 0, stream>>>(q, kva, kv, positions, qf, kf, vb);
    // 10. attention (fp32)
    attn_kernel<<<dim3(T_, NH), blk, 0, stream>>>(qf, kf, vb, ob);
    // 11. attn_out = ob @ o_w (1024 x 2048 x 1024)  [split: feeds routing]
    gemm_bf16<true><<<dim3(2048 / 64, T_ / 128), blk, 0, stream>>>(ob, o_w, att, T_, 2048, 1024);
    // 12. resid += attn_out
    add_inplace_kernel<<<2048, blk, 0, stream>>>(x0, att, T_ * 2048);
    // 13. h2 = rmsnorm(resid) -> h
    rmsnorm_kernel<<<T_, blk, 0, stream>>>(x0, 2048, 2048, post_ln_w, h, 2048);
    // 14. routing (fp32)
    routing_kernel<<<T_, blk, 0, stream>>>(h, gate_w, gate_bias, topidx, topw);
    // 15. sort by expert (128-row tiles)
    sort_kernel<<<1, 512, 0, stream>>>(topidx, sorted_t, slotpos, tilemap);
    // 16. gather h2 rows per slot
    gather_kernel<<<2 * T_, blk, 0, stream>>>(h, sorted_t, gath);
    // 17. MoE gate / up (plain bf16, post-routing)
    moe_gemm_bf16<<<dim3(1024 / 64, MAXTILES), blk, 0, stream>>>(gath, exp_g, mg, tilemap, 2048, 1024);
    moe_gemm_bf16<<<dim3(1024 / 64, MAXTILES), blk, 0, stream>>>(gath, exp_u, mu, tilemap, 2048, 1024);
    // 18. act = silu(g) * u
    silu_mul_kernel<<<2048, blk, 0, stream>>>(mg, mu, 2048 * 1024);
    // 19. MoE down
    moe_gemm_bf16<<<dim3(2048 / 64, MAXTILES), blk, 0, stream>>>(mg, exp_d, md, tilemap, 1024, 2048);
    // 20. shared MLP (plain bf16)
    gemm_bf16<false><<<dim3(1024 / 64, T_ / 128), blk, 0, stream>>>(h, sh_g, sg, T_, 1024, 2048);
    gemm_bf16<false><<<dim3(1024 / 64, T_ / 128), blk, 0, stream>>>(h, sh_u, su, T_, 1024, 2048);
    silu_mul_kernel<<<1024, blk, 0, stream>>>(sg, su, T_ * 1024);
    gemm_bf16<false><<<dim3(2048 / 64, T_ / 128), blk, 0, stream>>>(sg, sh_d, sho, T_, 2048, 1024);
    // 21. final combine -> f32
    final_kernel<<<T_, blk, 0, stream>>>(x0, sho, md, slotpos, topw, out);
}

// Round 5
// 1311.236 us; speedup vs baseline: 1.7069x; 1.4355x over previous
//
#include <hip/hip_runtime.h>
#include <hip/hip_bf16.h>
#include <math.h>

constexpr int T_ = 1024;
constexpr int HDIM = 2048;
constexpr int NH = 16;
constexpr int QKD = 96;   // NOPE+ROPE
constexpr int VD = 64;
constexpr int MAXTILES = 24;   // MoE 128-row tiles: sum ceil(c_e/128) <= 8 + 2048/128 = 24
constexpr float EPSF = 1e-6f;

using f32x4 = __attribute__((ext_vector_type(4))) float;
using s16x8 = __attribute__((ext_vector_type(8))) short;
using s16x4 = __attribute__((ext_vector_type(4))) short;

// ---------------- workspace layout (offsets in floats) ----------------
constexpr size_t OF_CAT  = 0;                           // T*4096 cat_in; later gather (2048x2048)
constexpr size_t OF_X0   = OF_CAT + (size_t)T_ * 4096;  // T*2048 resid
constexpr size_t OF_H    = OF_X0  + (size_t)T_ * 2048;  // T*2048 h, later h2
constexpr size_t OF_QA   = OF_H   + (size_t)T_ * 2048;  // T*512  qa (normed); later SG/SU
constexpr size_t OF_Q    = OF_QA  + (size_t)T_ * 512;   // T*1536 q_a raw, then q
constexpr size_t OF_KVA  = OF_Q   + (size_t)T_ * 1536;  // T*288
constexpr size_t OF_KVCN = OF_KVA + (size_t)T_ * 288;   // T*256
constexpr size_t OF_KV   = OF_KVCN+ (size_t)T_ * 256;   // T*2048; later SHO
constexpr size_t OF_QF   = OF_KV  + (size_t)T_ * 2048;  // T*1536; later MD start
constexpr size_t OF_KF   = OF_QF  + (size_t)T_ * 1536;  // T*1536
constexpr size_t OF_VB   = OF_KF  + (size_t)T_ * 1536;  // T*1024
constexpr size_t OF_OB   = OF_VB  + (size_t)T_ * 1024;  // T*1024
constexpr size_t OF_ATT  = OF_OB  + (size_t)T_ * 1024;  // T*2048
constexpr size_t OF_MG   = OF_ATT + (size_t)T_ * 2048;  // 2048*1024
constexpr size_t OF_MU   = OF_MG  + (size_t)2048 * 1024;// 2048*1024
constexpr size_t OF_ROUT = OF_MU  + (size_t)2048 * 1024;
// aliases (lifetime-disjoint)
constexpr size_t OF_GATH = OF_CAT;                      // 2048x2048 gathered h2 rows
constexpr size_t OF_MD   = OF_QF;                       // 2048x2048 (spans QF+KF+VB)
constexpr size_t OF_SG   = OF_QA;                       // T*1024
constexpr size_t OF_SU   = OF_QA + (size_t)T_ * 1024;   // T*1024
constexpr size_t OF_SHO  = OF_KV;                       // T*2048

// ---------------- helpers ----------------
__device__ __forceinline__ short f2bf(float f) {
    union { float f; unsigned u; } x; x.f = f;
    unsigned r = x.u + 0x7fffu + ((x.u >> 16) & 1u);   // RNE
    return (short)(r >> 16);
}
__device__ __forceinline__ float bf2f(short h) {
    union { unsigned u; float f; } x; x.u = ((unsigned)(unsigned short)h) << 16; return x.f;
}

__device__ __forceinline__ float block_sum(float v) {
    __shared__ float sbuf[9];
    int lane = threadIdx.x & 63;
    int wid  = threadIdx.x >> 6;
#pragma unroll
    for (int off = 32; off > 0; off >>= 1) v += __shfl_down(v, off);
    __syncthreads();
    if (lane == 0) sbuf[wid] = v;
    __syncthreads();
    if (threadIdx.x == 0) {
        float s = 0.f;
        int nw = blockDim.x >> 6;
        for (int i = 0; i < nw; i++) s += sbuf[i];
        sbuf[8] = s;
    }
    __syncthreads();
    return sbuf[8];
}

// ---------------- embedding + rmsnorm + concat ----------------
__global__ void embed_cat_kernel(const int* __restrict__ ids, const float* __restrict__ embed,
                                 const float* __restrict__ enorm, const float* __restrict__ prev,
                                 const float* __restrict__ hnorm, float* __restrict__ cat) {
    int t = blockIdx.x;
    const float* e = embed + (size_t)ids[t] * HDIM;
    float ss = 0.f;
    for (int i = threadIdx.x; i < HDIM; i += blockDim.x) { float v = e[i]; ss += v * v; }
    float r = rsqrtf(block_sum(ss) / HDIM + EPSF);
    for (int i = threadIdx.x; i < HDIM; i += blockDim.x)
        cat[(size_t)t * 4096 + i] = e[i] * r * enorm[i];
    const float* p = prev + (size_t)t * HDIM;
    ss = 0.f;
    for (int i = threadIdx.x; i < HDIM; i += blockDim.x) { float v = p[i]; ss += v * v; }
    r = rsqrtf(block_sum(ss) / HDIM + EPSF);
    for (int i = threadIdx.x; i < HDIM; i += blockDim.x)
        cat[(size_t)t * 4096 + 2048 + i] = p[i] * r * hnorm[i];
}

// ---------------- generic rmsnorm ----------------
__global__ void rmsnorm_kernel(const float* __restrict__ in, int in_stride, int width,
                               const float* __restrict__ w, float* __restrict__ out, int out_stride) {
    int t = blockIdx.x;
    const float* x = in + (size_t)t * in_stride;
    float ss = 0.f;
    for (int i = threadIdx.x; i < width; i += blockDim.x) { float v = x[i]; ss += v * v; }
    float r = rsqrtf(block_sum(ss) / width + EPSF);
    float* o = out + (size_t)t * out_stride;
    for (int i = threadIdx.x; i < width; i += blockDim.x) o[i] = x[i] * r * w[i];
}

// =====================================================================
// bf16 MFMA GEMM (as round 4, verified): SPLIT=true -> ~fp32 accuracy.
// =====================================================================
template<bool SPLIT>
__global__ __launch_bounds__(256) void gemm_bf16(const float* __restrict__ A, const float* __restrict__ B,
                                                 float* __restrict__ C, int M, int N, int K) {
    __shared__ short As[SPLIT ? 2 : 1][128][72];
    __shared__ short Bs[SPLIT ? 2 : 1][64][72];
    const int tid = threadIdx.x;
    const int lane = tid & 63, wid = tid >> 6;
    const int g = lane >> 4, li = lane & 15;
    const int wm = wid >> 1, wn = wid & 1;        // 2x2 wave grid
    const int row0 = blockIdx.y * 128, col0 = blockIdx.x * 64;

    f32x4 acc[4][2];
#pragma unroll
    for (int mi = 0; mi < 4; mi++)
#pragma unroll
        for (int ni = 0; ni < 2; ni++)
#pragma unroll
            for (int r = 0; r < 4; r++) acc[mi][ni][r] = 0.f;

    const int sar = tid >> 3, sak = (tid & 7) << 3;    // A staging: 4 chunks stride 32 rows
    const int skb = (tid >> 4) << 2, snb = (tid & 15) << 2; // B staging

    for (int k0 = 0; k0 < K; k0 += 64) {
        // ---- stage A ----
#pragma unroll
        for (int i = 0; i < 4; i++) {
            int ar = sar + i * 32;
            const float* src = A + (size_t)(row0 + ar) * K + k0 + sak;
            float4 f0 = *(const float4*)src;
            float4 f1 = *(const float4*)(src + 4);
            float vals[8] = {f0.x, f0.y, f0.z, f0.w, f1.x, f1.y, f1.z, f1.w};
            s16x8 vh, vl;
#pragma unroll
            for (int j = 0; j < 8; j++) {
                short hh = f2bf(vals[j]);
                vh[j] = hh;
                if constexpr (SPLIT) vl[j] = f2bf(vals[j] - bf2f(hh));
            }
            *(s16x8*)&As[0][ar][sak] = vh;
            if constexpr (SPLIT) *(s16x8*)&As[1][ar][sak] = vl;
        }
        // ---- stage B transposed ----
        {
            float4 r4[4];
#pragma unroll
            for (int kk = 0; kk < 4; kk++) {
                const float* brow = B + (size_t)(k0 + skb + kk) * N;
                int gn = col0 + snb;
                if (gn + 3 < N) r4[kk] = *(const float4*)(brow + gn);
                else {
                    r4[kk].x = (gn + 0 < N) ? brow[gn + 0] : 0.f;
                    r4[kk].y = (gn + 1 < N) ? brow[gn + 1] : 0.f;
                    r4[kk].z = (gn + 2 < N) ? brow[gn + 2] : 0.f;
                    r4[kk].w = (gn + 3 < N) ? brow[gn + 3] : 0.f;
                }
            }
#pragma unroll
            for (int n = 0; n < 4; n++) {
                s16x4 wh, wl;
#pragma unroll
                for (int kk = 0; kk < 4; kk++) {
                    float f = (&r4[kk].x)[n];
                    short hh = f2bf(f);
                    wh[kk] = hh;
                    if constexpr (SPLIT) wl[kk] = f2bf(f - bf2f(hh));
                }
                *(s16x4*)&Bs[0][snb + n][skb] = wh;
                if constexpr (SPLIT) *(s16x4*)&Bs[1][snb + n][skb] = wl;
            }
        }
        __syncthreads();
        // ---- compute: 2 k-steps of 32 ----
#pragma unroll
        for (int kk = 0; kk < 64; kk += 32) {
            s16x8 ah[4], bh[2];
#pragma unroll
            for (int mi = 0; mi < 4; mi++) ah[mi] = *(const s16x8*)&As[0][wm * 64 + mi * 16 + li][kk + g * 8];
#pragma unroll
            for (int ni = 0; ni < 2; ni++) bh[ni] = *(const s16x8*)&Bs[0][wn * 32 + ni * 16 + li][kk + g * 8];
            if constexpr (SPLIT) {
                s16x8 al[4], bl[2];
#pragma unroll
                for (int mi = 0; mi < 4; mi++) al[mi] = *(const s16x8*)&As[1][wm * 64 + mi * 16 + li][kk + g * 8];
#pragma unroll
                for (int ni = 0; ni < 2; ni++) bl[ni] = *(const s16x8*)&Bs[1][wn * 32 + ni * 16 + li][kk + g * 8];
#pragma unroll
                for (int mi = 0; mi < 4; mi++)
#pragma unroll
                    for (int ni = 0; ni < 2; ni++) {
                        acc[mi][ni] = __builtin_amdgcn_mfma_f32_16x16x32_bf16(ah[mi], bh[ni], acc[mi][ni], 0, 0, 0);
                        acc[mi][ni] = __builtin_amdgcn_mfma_f32_16x16x32_bf16(al[mi], bh[ni], acc[mi][ni], 0, 0, 0);
                        acc[mi][ni] = __builtin_amdgcn_mfma_f32_16x16x32_bf16(ah[mi], bl[ni], acc[mi][ni], 0, 0, 0);
                    }
            } else {
#pragma unroll
                for (int mi = 0; mi < 4; mi++)
#pragma unroll
                    for (int ni = 0; ni < 2; ni++)
                        acc[mi][ni] = __builtin_amdgcn_mfma_f32_16x16x32_bf16(ah[mi], bh[ni], acc[mi][ni], 0, 0, 0);
            }
        }
        __syncthreads();
    }
    // ---- epilogue: C/D map col=lane&15, row=(lane>>4)*4+reg ----
#pragma unroll
    for (int mi = 0; mi < 4; mi++)
#pragma unroll
        for (int ni = 0; ni < 2; ni++) {
            int gc = col0 + wn * 32 + ni * 16 + li;
            if (gc < N) {
#pragma unroll
                for (int r = 0; r < 4; r++) {
                    int gr = row0 + wm * 64 + mi * 16 + g * 4 + r;
                    C[(size_t)gr * N + gc] = acc[mi][ni][r];
                }
            }
        }
}

// ---------------- MoE grouped GEMM, plain bf16 (post-routing) ----------------
__global__ __launch_bounds__(256) void moe_gemm_bf16(const float* __restrict__ Abase, const float* __restrict__ Wall,
                                                     float* __restrict__ Cbase, const int4* __restrict__ tilemap,
                                                     int K, int N) {
    int4 tm = tilemap[blockIdx.y];
    int nrows = tm.z;
    if (nrows == 0) return;
    const float* A = Abase + (size_t)tm.y * K;
    float* C = Cbase + (size_t)tm.y * N;
    const float* B = Wall + (size_t)tm.x * K * N;

    alignas(16) __shared__ short As[128][72];
    alignas(16) __shared__ short Bs[64][72];
    const int tid = threadIdx.x;
    const int lane = tid & 63, wid = tid >> 6;
    const int g = lane >> 4, li = lane & 15;
    const int wm = wid >> 1, wn = wid & 1;
    const int col0 = blockIdx.x * 64;

    f32x4 acc[4][2];
#pragma unroll
    for (int mi = 0; mi < 4; mi++)
#pragma unroll
        for (int ni = 0; ni < 2; ni++)
#pragma unroll
            for (int r = 0; r < 4; r++) acc[mi][ni][r] = 0.f;

    const int sar = tid >> 3, sak = (tid & 7) << 3;
    const int skb = (tid >> 4) << 2, snb = (tid & 15) << 2;

    for (int k0 = 0; k0 < K; k0 += 64) {
#pragma unroll
        for (int i = 0; i < 4; i++) {
            int ar = sar + i * 32;
            s16x8 v;
            if (ar < nrows) {
                const float* src = A + (size_t)ar * K + k0 + sak;
                float4 f0 = *(const float4*)src;
                float4 f1 = *(const float4*)(src + 4);
                v[0] = f2bf(f0.x); v[1] = f2bf(f0.y); v[2] = f2bf(f0.z); v[3] = f2bf(f0.w);
                v[4] = f2bf(f1.x); v[5] = f2bf(f1.y); v[6] = f2bf(f1.z); v[7] = f2bf(f1.w);
            } else {
#pragma unroll
                for (int j = 0; j < 8; j++) v[j] = 0;
            }
            *(s16x8*)&As[ar][sak] = v;
        }
        {
            float4 r4[4];
#pragma unroll
            for (int kk = 0; kk < 4; kk++)
                r4[kk] = *(const float4*)(B + (size_t)(k0 + skb + kk) * N + col0 + snb);
#pragma unroll
            for (int n = 0; n < 4; n++) {
                s16x4 w;
                w[0] = f2bf((&r4[0].x)[n]); w[1] = f2bf((&r4[1].x)[n]);
                w[2] = f2bf((&r4[2].x)[n]); w[3] = f2bf((&r4[3].x)[n]);
                *(s16x4*)&Bs[snb + n][skb] = w;
            }
        }
        __syncthreads();
#pragma unroll
        for (int kk = 0; kk < 64; kk += 32) {
            s16x8 a[4], b[2];
#pragma unroll
            for (int mi = 0; mi < 4; mi++) a[mi] = *(const s16x8*)&As[wm * 64 + mi * 16 + li][kk + g * 8];
#pragma unroll
            for (int ni = 0; ni < 2; ni++) b[ni] = *(const s16x8*)&Bs[wn * 32 + ni * 16 + li][kk + g * 8];
#pragma unroll
            for (int mi = 0; mi < 4; mi++)
#pragma unroll
                for (int ni = 0; ni < 2; ni++)
                    acc[mi][ni] = __builtin_amdgcn_mfma_f32_16x16x32_bf16(a[mi], b[ni], acc[mi][ni], 0, 0, 0);
        }
        __syncthreads();
    }
#pragma unroll
    for (int mi = 0; mi < 4; mi++)
#pragma unroll
        for (int ni = 0; ni < 2; ni++) {
            int gc = col0 + wn * 32 + ni * 16 + li;
#pragma unroll
            for (int r = 0; r < 4; r++) {
                int gr = wm * 64 + mi * 16 + g * 4 + r;
                if (gr < nrows) C[(size_t)gr * N + gc] = acc[mi][ni][r];
            }
        }
}

// ---------------- RoPE + build qf/kf/v ----------------
__global__ void prep_qkv_kernel(const float* __restrict__ q, const float* __restrict__ kva,
                                const float* __restrict__ kv, const int* __restrict__ positions,
                                float* __restrict__ qf, float* __restrict__ kf, float* __restrict__ vb) {
    int t = blockIdx.x;
    __shared__ float cs[16], sn[16];
    if (threadIdx.x < 16) {
        float invf = powf(10000.f, -(float)(2 * threadIdx.x) / 32.f);
        float fr = (float)positions[t] * invf;
        cs[threadIdx.x] = cosf(fr);
        sn[threadIdx.x] = sinf(fr);
    }
    __syncthreads();
    for (int i = threadIdx.x; i < NH * QKD; i += blockDim.x) {
        int h = i / QKD, d = i % QKD;
        float val;
        if (d < 64) val = q[(size_t)t * 1536 + h * QKD + d];
        else {
            int r = d - 64, pr = r >> 1;
            float x1 = q[(size_t)t * 1536 + h * QKD + 64 + 2 * pr];
            float x2 = q[(size_t)t * 1536 + h * QKD + 64 + 2 * pr + 1];
            val = (r & 1) ? (x1 * sn[pr] + x2 * cs[pr]) : (x1 * cs[pr] - x2 * sn[pr]);
        }
        qf[(size_t)t * 1536 + i] = val;
    }
    for (int i = threadIdx.x; i < NH * QKD; i += blockDim.x) {
        int h = i / QKD, d = i % QKD;
        float val;
        if (d < 64) val = kv[(size_t)t * 2048 + h * 128 + d];
        else {
            int r = d - 64, pr = r >> 1;
            float x1 = kva[(size_t)t * 288 + 256 + 2 * pr];
            float x2 = kva[(size_t)t * 288 + 256 + 2 * pr + 1];
            val = (r & 1) ? (x1 * sn[pr] + x2 * cs[pr]) : (x1 * cs[pr] - x2 * sn[pr]);
        }
        kf[(size_t)t * 1536 + i] = val;
    }
    for (int i = threadIdx.x; i < NH * VD; i += blockDim.x) {
        int h = i / VD, d = i % VD;
        vb[(size_t)t * 1024 + i] = kv[(size_t)t * 2048 + h * 128 + 64 + d];
    }
}

// =====================================================================
// MFMA flash attention. Block = (Q-tile of 64 rows, head); 4 waves x 16 rows.
// K/V tiles (64 keys) staged as split bf16 (hi+lo) in LDS; QK^T and PV are
// 3-MFMA splits (~fp32 accuracy -> routing decisions unperturbed).
// Online softmax is wave-local: C-layout puts all 64 key-scores of a q-row
// in one 16-lane group -> shfl_xor(1,2,4,8) row reduce.
// =====================================================================
__global__ __launch_bounds__(256) void attn_mfma_kernel(const float* __restrict__ qf,
                                                        const float* __restrict__ kf,
                                                        const float* __restrict__ vb,
                                                        float* __restrict__ ob) {
    __shared__ short K_hi[64][104], K_lo[64][104];
    __shared__ short Vt_hi[64][72], Vt_lo[64][72];
    __shared__ short P_hi[4][16][72], P_lo[4][16][72];
    const int qt = blockIdx.x, h = blockIdx.y;
    const int tid = threadIdx.x, lane = tid & 63, w = tid >> 6;
    const int g = lane >> 4, li = lane & 15;

    // ---- Q fragments (row = w*16+li, k-octet = g*8) ----
    s16x8 q_hi[3], q_lo[3];
    {
        const float* qsrc = qf + (size_t)(qt * 64 + w * 16 + li) * 1536 + h * QKD;
#pragma unroll
        for (int ks = 0; ks < 3; ks++) {
            float4 f0 = *(const float4*)(qsrc + ks * 32 + g * 8);
            float4 f1 = *(const float4*)(qsrc + ks * 32 + g * 8 + 4);
            float vals[8] = {f0.x, f0.y, f0.z, f0.w, f1.x, f1.y, f1.z, f1.w};
#pragma unroll
            for (int j = 0; j < 8; j++) {
                short hh = f2bf(vals[j]);
                q_hi[ks][j] = hh;
                q_lo[ks][j] = f2bf(vals[j] - bf2f(hh));
            }
        }
    }

    f32x4 acc_o[4];
#pragma unroll
    for (int nc = 0; nc < 4; nc++)
#pragma unroll
        for (int r = 0; r < 4; r++) acc_o[nc][r] = 0.f;
    float m4[4] = {-1e30f, -1e30f, -1e30f, -1e30f};
    float l4[4] = {0.f, 0.f, 0.f, 0.f};
    const float scale = 0.102062072616f;   // 96^-0.5

    for (int kt = 0; kt <= qt; kt++) {
        // ---- stage K tile (64 x 96 f32 -> hi/lo bf16) ----
#pragma unroll
        for (int it = 0; it < 6; it++) {
            int gi = tid + it * 256;
            int key = gi / 24, c = gi % 24;
            float4 f = *(const float4*)(kf + (size_t)(kt * 64 + key) * 1536 + h * QKD + c * 4);
            float vals[4] = {f.x, f.y, f.z, f.w};
            s16x4 vh, vl;
#pragma unroll
            for (int j = 0; j < 4; j++) {
                short hh = f2bf(vals[j]);
                vh[j] = hh;
                vl[j] = f2bf(vals[j] - bf2f(hh));
            }
            *(s16x4*)&K_hi[key][c * 4] = vh;
            *(s16x4*)&K_lo[key][c * 4] = vl;
        }
        // ---- stage V tile transposed (Vt[vd][key]) ----
#pragma unroll
        for (int it = 0; it < 4; it++) {
            int gi = tid + it * 256;
            int key = gi >> 4, v4 = (gi & 15) << 2;
            float4 f = *(const float4*)(vb + (size_t)(kt * 64 + key) * 1024 + h * VD + v4);
            float vals[4] = {f.x, f.y, f.z, f.w};
#pragma unroll
            for (int j = 0; j < 4; j++) {
                short hh = f2bf(vals[j]);
                Vt_hi[v4 + j][key] = hh;
                Vt_lo[v4 + j][key] = f2bf(vals[j] - bf2f(hh));
            }
        }
        __syncthreads();

        // ---- QK^T: S[16 q][64 keys], split 3-MFMA ----
        f32x4 acc_s[4];
#pragma unroll
        for (int kc = 0; kc < 4; kc++)
#pragma unroll
            for (int r = 0; r < 4; r++) acc_s[kc][r] = 0.f;
#pragma unroll
        for (int ks = 0; ks < 3; ks++) {
#pragma unroll
            for (int kc = 0; kc < 4; kc++) {
                s16x8 kh = *(const s16x8*)&K_hi[kc * 16 + li][ks * 32 + g * 8];
                s16x8 kl = *(const s16x8*)&K_lo[kc * 16 + li][ks * 32 + g * 8];
                acc_s[kc] = __builtin_amdgcn_mfma_f32_16x16x32_bf16(q_hi[ks], kh, acc_s[kc], 0, 0, 0);
                acc_s[kc] = __builtin_amdgcn_mfma_f32_16x16x32_bf16(q_lo[ks], kh, acc_s[kc], 0, 0, 0);
                acc_s[kc] = __builtin_amdgcn_mfma_f32_16x16x32_bf16(q_hi[ks], kl, acc_s[kc], 0, 0, 0);
            }
        }
        // scale + causal mask (diagonal tile only)
#pragma unroll
        for (int kc = 0; kc < 4; kc++)
#pragma unroll
            for (int r = 0; r < 4; r++) acc_s[kc][r] *= scale;
        if (kt == qt) {
#pragma unroll
            for (int kc = 0; kc < 4; kc++) {
                int key = kt * 64 + kc * 16 + li;
#pragma unroll
                for (int r = 0; r < 4; r++) {
                    int qr = qt * 64 + w * 16 + g * 4 + r;
                    if (key > qr) acc_s[kc][r] = -1e30f;
                }
            }
        }
        // ---- online softmax (wave-local; rows g*4+r live in group g) ----
        float tm[4];
#pragma unroll
        for (int r = 0; r < 4; r++)
            tm[r] = fmaxf(fmaxf(acc_s[0][r], acc_s[1][r]), fmaxf(acc_s[2][r], acc_s[3][r]));
#pragma unroll
        for (int off = 1; off < 16; off <<= 1)
#pragma unroll
            for (int r = 0; r < 4; r++) tm[r] = fmaxf(tm[r], __shfl_xor(tm[r], off));
        float alpha[4];
#pragma unroll
        for (int r = 0; r < 4; r++) {
            float mn = fmaxf(m4[r], tm[r]);
            alpha[r] = __expf(m4[r] - mn);
            m4[r] = mn;
        }
        float rs[4] = {0.f, 0.f, 0.f, 0.f};
#pragma unroll
        for (int kc = 0; kc < 4; kc++)
#pragma unroll
            for (int r = 0; r < 4; r++) {
                float p = __expf(acc_s[kc][r] - m4[r]);
                rs[r] += p;
                short hh = f2bf(p);
                P_hi[w][g * 4 + r][kc * 16 + li] = hh;
                P_lo[w][g * 4 + r][kc * 16 + li] = f2bf(p - bf2f(hh));
            }
#pragma unroll
        for (int off = 1; off < 16; off <<= 1)
#pragma unroll
            for (int r = 0; r < 4; r++) rs[r] += __shfl_xor(rs[r], off);
#pragma unroll
        for (int r = 0; r < 4; r++) l4[r] = l4[r] * alpha[r] + rs[r];
#pragma unroll
        for (int nc = 0; nc < 4; nc++)
#pragma unroll
            for (int r = 0; r < 4; r++) acc_o[nc][r] *= alpha[r];
        // ---- PV: O += P @ V (split 3-MFMA); P/V reads are wave-private ----
#pragma unroll
        for (int ks = 0; ks < 2; ks++) {
            s16x8 ph = *(const s16x8*)&P_hi[w][li][ks * 32 + g * 8];
            s16x8 pl = *(const s16x8*)&P_lo[w][li][ks * 32 + g * 8];
#pragma unroll
            for (int nc = 0; nc < 4; nc++) {
                s16x8 vh = *(const s16x8*)&Vt_hi[nc * 16 + li][ks * 32 + g * 8];
                s16x8 vl = *(const s16x8*)&Vt_lo[nc * 16 + li][ks * 32 + g * 8];
                acc_o[nc] = __builtin_amdgcn_mfma_f32_16x16x32_bf16(ph, vh, acc_o[nc], 0, 0, 0);
                acc_o[nc] = __builtin_amdgcn_mfma_f32_16x16x32_bf16(pl, vh, acc_o[nc], 0, 0, 0);
                acc_o[nc] = __builtin_amdgcn_mfma_f32_16x16x32_bf16(ph, vl, acc_o[nc], 0, 0, 0);
            }
        }
        __syncthreads();
    }
    // ---- epilogue: O / l -> ob ----
    float inv[4];
#pragma unroll
    for (int r = 0; r < 4; r++) inv[r] = 1.f / l4[r];
#pragma unroll
    for (int nc = 0; nc < 4; nc++)
#pragma unroll
        for (int r = 0; r < 4; r++)
            ob[(size_t)(qt * 64 + w * 16 + g * 4 + r) * 1024 + h * VD + nc * 16 + li] = acc_o[nc][r] * inv[r];
}

// ---------------- routing: gate logits -> sigmoid -> top2 ----------------
__global__ void routing_kernel(const float* __restrict__ h2, const float* __restrict__ gate_w,
                               const float* __restrict__ gate_bias, int* __restrict__ topidx,
                               float* __restrict__ topw) {
    int t = blockIdx.x;
    float acc[8] = {0.f, 0.f, 0.f, 0.f, 0.f, 0.f, 0.f, 0.f};
    for (int i = threadIdx.x; i < HDIM; i += blockDim.x) {
        float hv = h2[(size_t)t * HDIM + i];
        const float* g = gate_w + (size_t)i * 8;
#pragma unroll
        for (int e = 0; e < 8; e++) acc[e] = fmaf(hv, g[e], acc[e]);
    }
    __shared__ float logits[8];
    for (int e = 0; e < 8; e++) {
        float s = block_sum(acc[e]);
        if (threadIdx.x == 0) logits[e] = s;
    }
    __syncthreads();
    if (threadIdx.x == 0) {
        float sig[8], sc[8];
        for (int e = 0; e < 8; e++) {
            sig[e] = 1.f / (1.f + expf(-logits[e]));
            sc[e] = sig[e] + gate_bias[e];
        }
        int i0 = 0;
        for (int e = 1; e < 8; e++) if (sc[e] > sc[i0]) i0 = e;
        int i1 = -1;
        for (int e = 0; e < 8; e++) if (e != i0 && (i1 < 0 || sc[e] > sc[i1])) i1 = e;
        float w0 = sig[i0], w1 = sig[i1], s = w0 + w1 + 1e-20f;
        topidx[t * 2 + 0] = i0; topidx[t * 2 + 1] = i1;
        topw[t * 2 + 0] = w0 / s; topw[t * 2 + 1] = w1 / s;
    }
}

// ---------------- deterministic counting sort by expert + 128-row tile map ----------------
__global__ void sort_kernel(const int* __restrict__ topidx, int* __restrict__ sorted_t,
                            int* __restrict__ slotpos, int4* __restrict__ tilemap) {
    __shared__ int counts[8], offs[9];
    int wid = threadIdx.x >> 6, lane = threadIdx.x & 63;
    int cnt = 0;
    for (int base = 0; base < 2 * T_; base += 64) {
        int e = topidx[base + lane];
        unsigned long long m = __ballot(e == wid);
        cnt += __popcll(m);
    }
    if (lane == 0) counts[wid] = cnt;
    __syncthreads();
    if (threadIdx.x == 0) {
        offs[0] = 0;
        for (int e = 0; e < 8; e++) offs[e + 1] = offs[e] + counts[e];
    }
    __syncthreads();
    int pos = offs[wid];
    for (int base = 0; base < 2 * T_; base += 64) {
        int sl = base + lane;
        int e = topidx[sl];
        bool match = (e == wid);
        unsigned long long m = __ballot(match);
        if (match) {
            int before = __popcll(m & ((1ull << lane) - 1ull));
            int pp = pos + before;
            sorted_t[pp] = sl >> 1;
            slotpos[sl] = pp;
        }
        pos += __popcll(m);
    }
    __syncthreads();
    if (threadIdx.x == 0) {
        int nt = 0;
        for (int e = 0; e < 8; e++) {
            int c = counts[e], o = offs[e];
            for (int r = 0; r < c; r += 128) {
                tilemap[nt] = make_int4(e, o + r, min(128, c - r), 0);
                nt++;
            }
        }
        for (int i = nt; i < MAXTILES; i++) tilemap[i] = make_int4(0, 0, 0, 0);
    }
}

// ---------------- gather rows of h2 per sorted slot ----------------
__global__ void gather_kernel(const float* __restrict__ h2, const int* __restrict__ sorted_t,
                              float* __restrict__ gout) {
    int pp = blockIdx.x;
    int t = sorted_t[pp];
    const float4* src = (const float4*)(h2 + (size_t)t * HDIM);
    float4* dst = (float4*)(gout + (size_t)pp * HDIM);
    for (int i = threadIdx.x; i < HDIM / 4; i += blockDim.x) dst[i] = src[i];
}

// ---------------- elementwise ----------------
__global__ void silu_mul_kernel(float* __restrict__ g, const float* __restrict__ u, int n) {
    int stride = gridDim.x * blockDim.x;
    for (int i = blockIdx.x * blockDim.x + threadIdx.x; i < n; i += stride) {
        float x = g[i];
        g[i] = (x / (1.f + expf(-x))) * u[i];
    }
}

__global__ void add_inplace_kernel(float* __restrict__ x, const float* __restrict__ y, int n) {
    int stride = gridDim.x * blockDim.x;
    for (int i = blockIdx.x * blockDim.x + threadIdx.x; i < n; i += stride) x[i] += y[i];
}

// ---------------- final combine -> f32 out ----------------
__global__ void final_kernel(const float* __restrict__ resid, const float* __restrict__ sho,
                             const float* __restrict__ md, const int* __restrict__ slotpos,
                             const float* __restrict__ topw, float* __restrict__ out) {
    int t = blockIdx.x;
    int p0 = slotpos[t * 2 + 0], p1 = slotpos[t * 2 + 1];
    float w0 = topw[t * 2 + 0] * 2.5f, w1 = topw[t * 2 + 1] * 2.5f;
    for (int c = threadIdx.x; c < HDIM; c += blockDim.x) {
        float v = resid[(size_t)t * HDIM + c] + sho[(size_t)t * HDIM + c]
                + w0 * md[(size_t)p0 * HDIM + c] + w1 * md[(size_t)p1 * HDIM + c];
        out[(size_t)t * HDIM + c] = v;
    }
}

// ---------------- launcher ----------------
extern "C" void kernel_launch(void* const* d_in, const int* in_sizes, int n_in,
                              void* d_out, int out_size, void* d_ws, size_t ws_size,
                              hipStream_t stream) {
    (void)in_sizes; (void)n_in; (void)out_size; (void)ws_size;
    const int*   input_ids = (const int*)d_in[0];
    const int*   positions = (const int*)d_in[1];
    const float* prev      = (const float*)d_in[2];
    const float* embed     = (const float*)d_in[3];
    const float* enorm_w   = (const float*)d_in[4];
    const float* hnorm_w   = (const float*)d_in[5];
    const float* eh_proj_w = (const float*)d_in[6];
    const float* in_ln_w   = (const float*)d_in[7];
    const float* post_ln_w = (const float*)d_in[8];
    const float* q_a_w     = (const float*)d_in[9];
    const float* q_a_ln_w  = (const float*)d_in[10];
    const float* q_b_w     = (const float*)d_in[11];
    const float* kv_a_w    = (const float*)d_in[12];
    const float* kv_a_ln_w = (const float*)d_in[13];
    const float* kv_b_w    = (const float*)d_in[14];
    const float* o_w       = (const float*)d_in[15];
    const float* gate_w    = (const float*)d_in[16];
    const float* gate_bias = (const float*)d_in[17];
    const float* exp_g     = (const float*)d_in[18];
    const float* exp_u     = (const float*)d_in[19];
    const float* exp_d     = (const float*)d_in[20];
    const float* sh_g      = (const float*)d_in[21];
    const float* sh_u      = (const float*)d_in[22];
    const float* sh_d      = (const float*)d_in[23];
    float* out = (float*)d_out;

    float* ws = (float*)d_ws;
    float* cat   = ws + OF_CAT;
    float* x0    = ws + OF_X0;
    float* h     = ws + OF_H;       // h then h2
    float* qa    = ws + OF_QA;
    float* q     = ws + OF_Q;
    float* kva   = ws + OF_KVA;
    float* kvcn  = ws + OF_KVCN;
    float* kv    = ws + OF_KV;
    float* qf    = ws + OF_QF;
    float* kf    = ws + OF_KF;
    float* vb    = ws + OF_VB;
    float* ob    = ws + OF_OB;
    float* att   = ws + OF_ATT;
    float* mg    = ws + OF_MG;
    float* mu    = ws + OF_MU;
    float* gath  = ws + OF_GATH;
    float* md    = ws + OF_MD;
    float* sg    = ws + OF_SG;
    float* su    = ws + OF_SU;
    float* sho   = ws + OF_SHO;
    int*   ri       = (int*)(ws + OF_ROUT);
    int*   topidx   = ri;              // 2048
    int*   sorted_t = ri + 2048;       // 2048
    int*   slotpos  = ri + 4096;       // 2048
    int4*  tilemap  = (int4*)(ri + 6144); // MAXTILES * int4
    float* topw     = (float*)(ri + 6144 + 4 * MAXTILES); // 2048

    dim3 blk(256);

    // 1. embed + rmsnorm + concat
    embed_cat_kernel<<<T_, blk, 0, stream>>>(input_ids, embed, enorm_w, prev, hnorm_w, cat);
    // 2. x0 = cat @ eh_proj  (1024 x 2048 x 4096)  [split: feeds routing]
    gemm_bf16<true><<<dim3(2048 / 64, T_ / 128), blk, 0, stream>>>(cat, eh_proj_w, x0, T_, 2048, 4096);
    // 3. h = rmsnorm(x0)
    rmsnorm_kernel<<<T_, blk, 0, stream>>>(x0, 2048, 2048, in_ln_w, h, 2048);
    // 4. q_a raw = h @ q_a_w -> q buffer, then rmsnorm -> qa   [split]
    gemm_bf16<true><<<dim3(512 / 64, T_ / 128), blk, 0, stream>>>(h, q_a_w, q, T_, 512, 2048);
    rmsnorm_kernel<<<T_, blk, 0, stream>>>(q, 512, 512, q_a_ln_w, qa, 512);
    // 5. q = qa @ q_b_w  (1024 x 1536 x 512)  [split]
    gemm_bf16<true><<<dim3(1536 / 64, T_ / 128), blk, 0, stream>>>(qa, q_b_w, q, T_, 1536, 512);
    // 6. kva = h @ kv_a_w (1024 x 288 x 2048)  [split]
    gemm_bf16<true><<<dim3(5, T_ / 128), blk, 0, stream>>>(h, kv_a_w, kva, T_, 288, 2048);
    // 7. kvcn = rmsnorm(kva[:, :256])
    rmsnorm_kernel<<<T_, blk, 0, stream>>>(kva, 288, 256, kv_a_ln_w, kvcn, 256);
    // 8. kv = kvcn @ kv_b_w (1024 x 2048 x 256)  [split]
    gemm_bf16<true><<<dim3(2048 / 64, T_ / 128), blk, 0, stream>>>(kvcn, kv_b_w, kv, T_, 2048, 256);
    // 9. rope + build qf/kf/v
    prep_qkv_kernel<<<T_, blk, 0, stream>>>(q, kva, kv, positions, qf, kf, vb);
    // 10. MFMA flash attention
    attn_mfma_kernel<<<dim3(T_ / 64, NH), blk, 0, stream>>>(qf, kf, vb, ob);
    // 11. attn_out = ob @ o_w (1024 x 2048 x 1024)  [split: feeds routing]
    gemm_bf16<true><<<dim3(2048 / 64, T_ / 128), blk, 0, stream>>>(ob, o_w, att, T_, 2048, 1024);
    // 12. resid += attn_out
    add_inplace_kernel<<<2048, blk, 0, stream>>>(x0, att, T_ * 2048);
    // 13. h2 = rmsnorm(resid) -> h
    rmsnorm_kernel<<<T_, blk, 0, stream>>>(x0, 2048, 2048, post_ln_w, h, 2048);
    // 14. routing (fp32)
    routing_kernel<<<T_, blk, 0, stream>>>(h, gate_w, gate_bias, topidx, topw);
    // 15. sort by expert (128-row tiles)
    sort_kernel<<<1, 512, 0, stream>>>(topidx, sorted_t, slotpos, tilemap);
    // 16. gather h2 rows per slot
    gather_kernel<<<2 * T_, blk, 0, stream>>>(h, sorted_t, gath);
    // 17. MoE gate / up (plain bf16, post-routing)
    moe_gemm_bf16<<<dim3(1024 / 64, MAXTILES), blk, 0, stream>>>(gath, exp_g, mg, tilemap, 2048, 1024);
    moe_gemm_bf16<<<dim3(1024 / 64, MAXTILES), blk, 0, stream>>>(gath, exp_u, mu, tilemap, 2048, 1024);
    // 18. act = silu(g) * u
    silu_mul_kernel<<<2048, blk, 0, stream>>>(mg, mu, 2048 * 1024);
    // 19. MoE down
    moe_gemm_bf16<<<dim3(2048 / 64, MAXTILES), blk, 0, stream>>>(mg, exp_d, md, tilemap, 1024, 2048);
    // 20. shared MLP (plain bf16)
    gemm_bf16<false><<<dim3(1024 / 64, T_ / 128), blk, 0, stream>>>(h, sh_g, sg, T_, 1024, 2048);
    gemm_bf16<false><<<dim3(1024 / 64, T_ / 128), blk, 0, stream>>>(h, sh_u, su, T_, 1024, 2048);
    silu_mul_kernel<<<1024, blk, 0, stream>>>(sg, su, T_ * 1024);
    gemm_bf16<false><<<dim3(2048 / 64, T_ / 128), blk, 0, stream>>>(sg, sh_d, sho, T_, 2048, 1024);
    // 21. final combine -> f32
    final_kernel<<<T_, blk, 0, stream>>>(x0, sho, md, slotpos, topw, out);
}

// Round 6
// 841.559 us; speedup vs baseline: 2.6595x; 1.5581x over previous
//
#include <hip/hip_runtime.h>
#include <hip/hip_bf16.h>
#include <math.h>

constexpr int T_ = 1024;
constexpr int HDIM = 2048;
constexpr int NH = 16;
constexpr int QKD = 96;
constexpr int VD = 64;
constexpr int MAXTILES = 24;
constexpr float EPSF = 1e-6f;

using f32x4 = __attribute__((ext_vector_type(4))) float;
using s16x8 = __attribute__((ext_vector_type(8))) short;
using s16x4 = __attribute__((ext_vector_type(4))) short;

// ---------------- workspace layout (float offsets; bf16 buffers sized el/2) ----------------
constexpr size_t OF_CATH  = 0;                 // bf16 T*4096
constexpr size_t OF_CATL  = 2097152;
constexpr size_t OF_GATH  = 0;                 // f32 2048*2048 (alias cat planes; disjoint lifetime)
constexpr size_t OF_X0    = 4194304;           // f32 T*2048
constexpr size_t OF_H2    = 6291456;           // f32 T*2048
constexpr size_t OF_HH    = 8388608;           // bf16 T*2048
constexpr size_t OF_HL    = 9437184;
constexpr size_t OF_SHO   = 8388608;           // f32 T*2048 (alias h planes)
constexpr size_t OF_QRAW  = 10485760;          // f32 T*512
constexpr size_t OF_QBUF  = 11010048;          // f32 T*1536
constexpr size_t OF_KVA   = 12582912;          // f32 T*288
constexpr size_t OF_KVBUF = 12877824;          // f32 T*2048
constexpr size_t OF_MD    = 10485760;          // f32 2048*2048 (alias qraw..kvbuf)
constexpr size_t OF_QAH   = 14974976;          // bf16 T*512
constexpr size_t OF_QAL   = 15237120;
constexpr size_t OF_KVCNH = 15499264;          // bf16 T*256
constexpr size_t OF_KVCNL = 15630336;
constexpr size_t OF_QFH   = 15761408;          // bf16 T*1536
constexpr size_t OF_QFL   = 16547840;
constexpr size_t OF_KFH   = 17334272;
constexpr size_t OF_KFL   = 18120704;
constexpr size_t OF_VBH   = 18907136;          // bf16 T*1024
constexpr size_t OF_VBL   = 19431424;
constexpr size_t OF_MG    = 15761408;          // f32 2048*1024 (alias qf/kf planes)
constexpr size_t OF_MU    = 17858560;          // f32 2048*1024 (alias kf/vb planes)
constexpr size_t OF_OBH   = 19955712;          // bf16 T*1024
constexpr size_t OF_OBL   = 20480000;
constexpr size_t OF_ATT   = 21004288;          // f32 T*2048
constexpr size_t OF_SG    = 21004288;          // f32 T*1024 (alias att)
constexpr size_t OF_SU    = 22052864;          // f32 T*1024
constexpr size_t OF_H2BF  = 23101440;          // bf16 T*2048
constexpr size_t OF_SGACT = 24150016;          // bf16 T*1024
constexpr size_t OF_ROUT  = 24674304;          // ints
// weight planes (bf16)
constexpr size_t OF_EHTH  = 24682752;          // [2048][4096]
constexpr size_t OF_EHTL  = 28877056;
constexpr size_t OF_QATH  = 33071360;          // [512][2048]
constexpr size_t OF_QATL  = 33595648;
constexpr size_t OF_QBTH  = 34119936;          // [1536][512]
constexpr size_t OF_QBTL  = 34513152;
constexpr size_t OF_KVATH = 34906368;          // [320][2048]
constexpr size_t OF_KVATL = 35234048;
constexpr size_t OF_KVBTH = 35561728;          // [2048][256]
constexpr size_t OF_KVBTL = 35823872;
constexpr size_t OF_OWTH  = 36086016;          // [2048][1024]
constexpr size_t OF_OWTL  = 37134592;
constexpr size_t OF_SHGT  = 38183168;          // [1024][2048]
constexpr size_t OF_SHUT  = 39231744;
constexpr size_t OF_SHDT  = 40280320;          // [2048][1024]

// ---------------- helpers ----------------
__device__ __forceinline__ short f2bf(float f) {
    union { float f; unsigned u; } x; x.f = f;
    unsigned r = x.u + 0x7fffu + ((x.u >> 16) & 1u);
    return (short)(r >> 16);
}
__device__ __forceinline__ float bf2f(short h) {
    union { unsigned u; float f; } x; x.u = ((unsigned)(unsigned short)h) << 16; return x.f;
}
// LDS chunk swizzle: tile row stride 64 shorts (128B = 8 chunks of 16B); chunk ^= row&7
__device__ __forceinline__ int swz(int r, int k) {
    return (r << 6) + ((((k >> 3) ^ (r & 7)) << 3) | (k & 7));
}

__device__ __forceinline__ float block_sum(float v) {
    __shared__ float sbuf[9];
    int lane = threadIdx.x & 63;
    int wid  = threadIdx.x >> 6;
#pragma unroll
    for (int off = 32; off > 0; off >>= 1) v += __shfl_down(v, off);
    __syncthreads();
    if (lane == 0) sbuf[wid] = v;
    __syncthreads();
    if (threadIdx.x == 0) {
        float s = 0.f;
        int nw = blockDim.x >> 6;
        for (int i = 0; i < nw; i++) s += sbuf[i];
        sbuf[8] = s;
    }
    __syncthreads();
    return sbuf[8];
}

// ---------------- weight transpose + split: W[K][N] f32 -> [Npad][K] bf16 planes ----------------
__global__ void transpose_split_kernel(const float* __restrict__ W, short* __restrict__ Whi,
                                       short* __restrict__ Wlo, int K, int N, int split) {
    __shared__ float tile[64][65];
    int k0 = blockIdx.x * 64, n0 = blockIdx.y * 64;
    int tn = threadIdx.x & 63;
    int tk4 = threadIdx.x >> 6;
#pragma unroll 4
    for (int i = 0; i < 16; i++) {
        int kk = tk4 * 16 + i;
        int gn = n0 + tn;
        tile[kk][tn] = (gn < N) ? W[(size_t)(k0 + kk) * N + gn] : 0.f;
    }
    __syncthreads();
    int on = threadIdx.x >> 2;
    int oc = threadIdx.x & 3;
#pragma unroll 4
    for (int i = 0; i < 16; i++) {
        int kk = oc * 16 + i;
        float v = tile[kk][on];
        short hh = f2bf(v);
        size_t o = (size_t)(n0 + on) * K + k0 + kk;
        Whi[o] = hh;
        if (split) Wlo[o] = f2bf(v - bf2f(hh));
    }
}

// ---------------- embedding + rmsnorm + concat -> split planes ----------------
__global__ void embed_cat_kernel(const int* __restrict__ ids, const float* __restrict__ embed,
                                 const float* __restrict__ enorm, const float* __restrict__ prev,
                                 const float* __restrict__ hnorm, short* __restrict__ ch,
                                 short* __restrict__ cl) {
    int t = blockIdx.x;
    const float* e = embed + (size_t)ids[t] * HDIM;
    float ss = 0.f;
    for (int i = threadIdx.x; i < HDIM; i += blockDim.x) { float v = e[i]; ss += v * v; }
    float r = rsqrtf(block_sum(ss) / HDIM + EPSF);
    for (int i = threadIdx.x; i < HDIM; i += blockDim.x) {
        float v = e[i] * r * enorm[i];
        short hh = f2bf(v);
        ch[(size_t)t * 4096 + i] = hh;
        cl[(size_t)t * 4096 + i] = f2bf(v - bf2f(hh));
    }
    const float* p = prev + (size_t)t * HDIM;
    ss = 0.f;
    for (int i = threadIdx.x; i < HDIM; i += blockDim.x) { float v = p[i]; ss += v * v; }
    r = rsqrtf(block_sum(ss) / HDIM + EPSF);
    for (int i = threadIdx.x; i < HDIM; i += blockDim.x) {
        float v = p[i] * r * hnorm[i];
        short hh = f2bf(v);
        ch[(size_t)t * 4096 + 2048 + i] = hh;
        cl[(size_t)t * 4096 + 2048 + i] = f2bf(v - bf2f(hh));
    }
}

// ---------------- rmsnorm with optional f32 / hi / lo outputs ----------------
__global__ void rmsnorm_kernel(const float* __restrict__ in, int in_stride, int width,
                               const float* __restrict__ w, float* __restrict__ outf,
                               short* __restrict__ outh, short* __restrict__ outl, int out_stride) {
    int t = blockIdx.x;
    const float* x = in + (size_t)t * in_stride;
    float ss = 0.f;
    for (int i = threadIdx.x; i < width; i += blockDim.x) { float v = x[i]; ss += v * v; }
    float r = rsqrtf(block_sum(ss) / width + EPSF);
    size_t ob = (size_t)t * out_stride;
    for (int i = threadIdx.x; i < width; i += blockDim.x) {
        float v = x[i] * r * w[i];
        if (outf) outf[ob + i] = v;
        if (outh) {
            short hh = f2bf(v);
            outh[ob + i] = hh;
            if (outl) outl[ob + i] = f2bf(v - bf2f(hh));
        }
    }
}

// =====================================================================
// Plane GEMM: C[M][N] f32 = A(planes [M][K]) @ B^T(planes [Npad][K]).
// BM=128 BN=64 BK=64, 4 waves 2x2, mfma 16x16x32_bf16, XOR-swizzled LDS.
// SPLIT: 3-MFMA (AhBh + AlBh + AhBl) ~fp32 accuracy.
// =====================================================================
template<bool SPLIT>
__global__ __launch_bounds__(256) void gemm_planes(const short* __restrict__ Ahi, const short* __restrict__ Alo,
                                                   const short* __restrict__ Bhi, const short* __restrict__ Blo,
                                                   float* __restrict__ C, int M, int N, int K) {
    __shared__ short As[SPLIT ? 2 : 1][128 * 64];
    __shared__ short Bs[SPLIT ? 2 : 1][64 * 64];
    const int tid = threadIdx.x;
    const int lane = tid & 63, wid = tid >> 6;
    const int g = lane >> 4, li = lane & 15;
    const int wm = wid >> 1, wn = wid & 1;
    const int row0 = blockIdx.y * 128, col0 = blockIdx.x * 64;

    f32x4 acc[4][2];
#pragma unroll
    for (int mi = 0; mi < 4; mi++)
#pragma unroll
        for (int ni = 0; ni < 2; ni++)
#pragma unroll
            for (int r = 0; r < 4; r++) acc[mi][ni][r] = 0.f;

    for (int k0 = 0; k0 < K; k0 += 64) {
        // stage A: 1024 chunks (128 rows x 8), 4 per thread
#pragma unroll
        for (int i = 0; i < 4; i++) {
            int cid = i * 256 + tid;
            int r = cid >> 3, c = cid & 7;
            *(s16x8*)&As[0][swz(r, c * 8)] = *(const s16x8*)&Ahi[(size_t)(row0 + r) * K + k0 + c * 8];
            if constexpr (SPLIT)
                *(s16x8*)&As[1][swz(r, c * 8)] = *(const s16x8*)&Alo[(size_t)(row0 + r) * K + k0 + c * 8];
        }
        // stage B^T: 512 chunks (64 rows x 8), 2 per thread
#pragma unroll
        for (int i = 0; i < 2; i++) {
            int cid = i * 256 + tid;
            int r = cid >> 3, c = cid & 7;
            *(s16x8*)&Bs[0][swz(r, c * 8)] = *(const s16x8*)&Bhi[(size_t)(col0 + r) * K + k0 + c * 8];
            if constexpr (SPLIT)
                *(s16x8*)&Bs[1][swz(r, c * 8)] = *(const s16x8*)&Blo[(size_t)(col0 + r) * K + k0 + c * 8];
        }
        __syncthreads();
#pragma unroll
        for (int kk = 0; kk < 64; kk += 32) {
            s16x8 ah[4], bh[2];
#pragma unroll
            for (int mi = 0; mi < 4; mi++) ah[mi] = *(const s16x8*)&As[0][swz(wm * 64 + mi * 16 + li, kk + g * 8)];
#pragma unroll
            for (int ni = 0; ni < 2; ni++) bh[ni] = *(const s16x8*)&Bs[0][swz(wn * 32 + ni * 16 + li, kk + g * 8)];
            if constexpr (SPLIT) {
                s16x8 al[4], bl[2];
#pragma unroll
                for (int mi = 0; mi < 4; mi++) al[mi] = *(const s16x8*)&As[1][swz(wm * 64 + mi * 16 + li, kk + g * 8)];
#pragma unroll
                for (int ni = 0; ni < 2; ni++) bl[ni] = *(const s16x8*)&Bs[1][swz(wn * 32 + ni * 16 + li, kk + g * 8)];
#pragma unroll
                for (int mi = 0; mi < 4; mi++)
#pragma unroll
                    for (int ni = 0; ni < 2; ni++) {
                        acc[mi][ni] = __builtin_amdgcn_mfma_f32_16x16x32_bf16(ah[mi], bh[ni], acc[mi][ni], 0, 0, 0);
                        acc[mi][ni] = __builtin_amdgcn_mfma_f32_16x16x32_bf16(al[mi], bh[ni], acc[mi][ni], 0, 0, 0);
                        acc[mi][ni] = __builtin_amdgcn_mfma_f32_16x16x32_bf16(ah[mi], bl[ni], acc[mi][ni], 0, 0, 0);
                    }
            } else {
#pragma unroll
                for (int mi = 0; mi < 4; mi++)
#pragma unroll
                    for (int ni = 0; ni < 2; ni++)
                        acc[mi][ni] = __builtin_amdgcn_mfma_f32_16x16x32_bf16(ah[mi], bh[ni], acc[mi][ni], 0, 0, 0);
            }
        }
        __syncthreads();
    }
#pragma unroll
    for (int mi = 0; mi < 4; mi++)
#pragma unroll
        for (int ni = 0; ni < 2; ni++) {
            int gc = col0 + wn * 32 + ni * 16 + li;
            if (gc < N) {
#pragma unroll
                for (int r = 0; r < 4; r++) {
                    int gr = row0 + wm * 64 + mi * 16 + g * 4 + r;
                    C[(size_t)gr * N + gc] = acc[mi][ni][r];
                }
            }
        }
}

// ---------------- MoE grouped GEMM (unchanged from round 5, proven) ----------------
__global__ __launch_bounds__(256) void moe_gemm_bf16(const float* __restrict__ Abase, const float* __restrict__ Wall,
                                                     float* __restrict__ Cbase, const int4* __restrict__ tilemap,
                                                     int K, int N) {
    int4 tm = tilemap[blockIdx.y];
    int nrows = tm.z;
    if (nrows == 0) return;
    const float* A = Abase + (size_t)tm.y * K;
    float* C = Cbase + (size_t)tm.y * N;
    const float* B = Wall + (size_t)tm.x * K * N;

    alignas(16) __shared__ short As[128][72];
    alignas(16) __shared__ short Bs[64][72];
    const int tid = threadIdx.x;
    const int lane = tid & 63, wid = tid >> 6;
    const int g = lane >> 4, li = lane & 15;
    const int wm = wid >> 1, wn = wid & 1;
    const int col0 = blockIdx.x * 64;

    f32x4 acc[4][2];
#pragma unroll
    for (int mi = 0; mi < 4; mi++)
#pragma unroll
        for (int ni = 0; ni < 2; ni++)
#pragma unroll
            for (int r = 0; r < 4; r++) acc[mi][ni][r] = 0.f;

    const int sar = tid >> 3, sak = (tid & 7) << 3;
    const int skb = (tid >> 4) << 2, snb = (tid & 15) << 2;

    for (int k0 = 0; k0 < K; k0 += 64) {
#pragma unroll
        for (int i = 0; i < 4; i++) {
            int ar = sar + i * 32;
            s16x8 v;
            if (ar < nrows) {
                const float* src = A + (size_t)ar * K + k0 + sak;
                float4 f0 = *(const float4*)src;
                float4 f1 = *(const float4*)(src + 4);
                v[0] = f2bf(f0.x); v[1] = f2bf(f0.y); v[2] = f2bf(f0.z); v[3] = f2bf(f0.w);
                v[4] = f2bf(f1.x); v[5] = f2bf(f1.y); v[6] = f2bf(f1.z); v[7] = f2bf(f1.w);
            } else {
#pragma unroll
                for (int j = 0; j < 8; j++) v[j] = 0;
            }
            *(s16x8*)&As[ar][sak] = v;
        }
        {
            float4 r4[4];
#pragma unroll
            for (int kk = 0; kk < 4; kk++)
                r4[kk] = *(const float4*)(B + (size_t)(k0 + skb + kk) * N + col0 + snb);
#pragma unroll
            for (int n = 0; n < 4; n++) {
                s16x4 w;
                w[0] = f2bf((&r4[0].x)[n]); w[1] = f2bf((&r4[1].x)[n]);
                w[2] = f2bf((&r4[2].x)[n]); w[3] = f2bf((&r4[3].x)[n]);
                *(s16x4*)&Bs[snb + n][skb] = w;
            }
        }
        __syncthreads();
#pragma unroll
        for (int kk = 0; kk < 64; kk += 32) {
            s16x8 a[4], b[2];
#pragma unroll
            for (int mi = 0; mi < 4; mi++) a[mi] = *(const s16x8*)&As[wm * 64 + mi * 16 + li][kk + g * 8];
#pragma unroll
            for (int ni = 0; ni < 2; ni++) b[ni] = *(const s16x8*)&Bs[wn * 32 + ni * 16 + li][kk + g * 8];
#pragma unroll
            for (int mi = 0; mi < 4; mi++)
#pragma unroll
                for (int ni = 0; ni < 2; ni++)
                    acc[mi][ni] = __builtin_amdgcn_mfma_f32_16x16x32_bf16(a[mi], b[ni], acc[mi][ni], 0, 0, 0);
        }
        __syncthreads();
    }
#pragma unroll
    for (int mi = 0; mi < 4; mi++)
#pragma unroll
        for (int ni = 0; ni < 2; ni++) {
            int gc = col0 + wn * 32 + ni * 16 + li;
#pragma unroll
            for (int r = 0; r < 4; r++) {
                int gr = wm * 64 + mi * 16 + g * 4 + r;
                if (gr < nrows) C[(size_t)gr * N + gc] = acc[mi][ni][r];
            }
        }
}

// ---------------- RoPE + build qf/kf/v as split planes ----------------
__global__ void prep_qkv_kernel(const float* __restrict__ q, const float* __restrict__ kva,
                                const float* __restrict__ kv, const int* __restrict__ positions,
                                short* __restrict__ qfh, short* __restrict__ qfl,
                                short* __restrict__ kfh, short* __restrict__ kfl,
                                short* __restrict__ vbh, short* __restrict__ vbl) {
    int t = blockIdx.x;
    __shared__ float cs[16], sn[16];
    if (threadIdx.x < 16) {
        float invf = powf(10000.f, -(float)(2 * threadIdx.x) / 32.f);
        float fr = (float)positions[t] * invf;
        cs[threadIdx.x] = cosf(fr);
        sn[threadIdx.x] = sinf(fr);
    }
    __syncthreads();
    for (int i = threadIdx.x; i < NH * QKD; i += blockDim.x) {
        int h = i / QKD, d = i % QKD;
        float val;
        if (d < 64) val = q[(size_t)t * 1536 + h * QKD + d];
        else {
            int r = d - 64, pr = r >> 1;
            float x1 = q[(size_t)t * 1536 + h * QKD + 64 + 2 * pr];
            float x2 = q[(size_t)t * 1536 + h * QKD + 64 + 2 * pr + 1];
            val = (r & 1) ? (x1 * sn[pr] + x2 * cs[pr]) : (x1 * cs[pr] - x2 * sn[pr]);
        }
        short hh = f2bf(val);
        qfh[(size_t)t * 1536 + i] = hh;
        qfl[(size_t)t * 1536 + i] = f2bf(val - bf2f(hh));
    }
    for (int i = threadIdx.x; i < NH * QKD; i += blockDim.x) {
        int h = i / QKD, d = i % QKD;
        float val;
        if (d < 64) val = kv[(size_t)t * 2048 + h * 128 + d];
        else {
            int r = d - 64, pr = r >> 1;
            float x1 = kva[(size_t)t * 288 + 256 + 2 * pr];
            float x2 = kva[(size_t)t * 288 + 256 + 2 * pr + 1];
            val = (r & 1) ? (x1 * sn[pr] + x2 * cs[pr]) : (x1 * cs[pr] - x2 * sn[pr]);
        }
        short hh = f2bf(val);
        kfh[(size_t)t * 1536 + i] = hh;
        kfl[(size_t)t * 1536 + i] = f2bf(val - bf2f(hh));
    }
    for (int i = threadIdx.x; i < NH * VD; i += blockDim.x) {
        int h = i / VD, d = i % VD;
        float val = kv[(size_t)t * 2048 + h * 128 + 64 + d];
        short hh = f2bf(val);
        vbh[(size_t)t * 1024 + i] = hh;
        vbl[(size_t)t * 1024 + i] = f2bf(val - bf2f(hh));
    }
}

// =====================================================================
// MFMA flash attention (round-5 verified math; now reads/writes bf16 planes)
// =====================================================================
__global__ __launch_bounds__(256) void attn_mfma_kernel(const short* __restrict__ qfh, const short* __restrict__ qfl,
                                                        const short* __restrict__ kfh, const short* __restrict__ kfl,
                                                        const short* __restrict__ vbh, const short* __restrict__ vbl,
                                                        short* __restrict__ obh, short* __restrict__ obl) {
    __shared__ short K_hi[64][104], K_lo[64][104];
    __shared__ short Vt_hi[64][72], Vt_lo[64][72];
    __shared__ short P_hi[4][16][72], P_lo[4][16][72];
    const int qt = blockIdx.x, h = blockIdx.y;
    const int tid = threadIdx.x, lane = tid & 63, w = tid >> 6;
    const int g = lane >> 4, li = lane & 15;

    s16x8 q_hi[3], q_lo[3];
    {
        const short* qb_h = qfh + (size_t)(qt * 64 + w * 16 + li) * 1536 + h * QKD;
        const short* qb_l = qfl + (size_t)(qt * 64 + w * 16 + li) * 1536 + h * QKD;
#pragma unroll
        for (int ks = 0; ks < 3; ks++) {
            q_hi[ks] = *(const s16x8*)(qb_h + ks * 32 + g * 8);
            q_lo[ks] = *(const s16x8*)(qb_l + ks * 32 + g * 8);
        }
    }

    f32x4 acc_o[4];
#pragma unroll
    for (int nc = 0; nc < 4; nc++)
#pragma unroll
        for (int r = 0; r < 4; r++) acc_o[nc][r] = 0.f;
    float m4[4] = {-1e30f, -1e30f, -1e30f, -1e30f};
    float l4[4] = {0.f, 0.f, 0.f, 0.f};
    const float scale = 0.102062072616f;

    for (int kt = 0; kt <= qt; kt++) {
        // stage K tile: 768 chunks (64 keys x 12), 3/thread
#pragma unroll
        for (int it = 0; it < 3; it++) {
            int cid = it * 256 + tid;
            int key = cid / 12, c = cid % 12;
            *(s16x8*)&K_hi[key][c * 8] = *(const s16x8*)&kfh[(size_t)(kt * 64 + key) * 1536 + h * QKD + c * 8];
            *(s16x8*)&K_lo[key][c * 8] = *(const s16x8*)&kfl[(size_t)(kt * 64 + key) * 1536 + h * QKD + c * 8];
        }
        // stage V transposed: 512 chunks (64 keys x 8), 2/thread
#pragma unroll
        for (int it = 0; it < 2; it++) {
            int cid = it * 256 + tid;
            int key = cid >> 3, vc = cid & 7;
            s16x8 vh = *(const s16x8*)&vbh[(size_t)(kt * 64 + key) * 1024 + h * VD + vc * 8];
            s16x8 vl = *(const s16x8*)&vbl[(size_t)(kt * 64 + key) * 1024 + h * VD + vc * 8];
#pragma unroll
            for (int j = 0; j < 8; j++) {
                Vt_hi[vc * 8 + j][key] = vh[j];
                Vt_lo[vc * 8 + j][key] = vl[j];
            }
        }
        __syncthreads();

        f32x4 acc_s[4];
#pragma unroll
        for (int kc = 0; kc < 4; kc++)
#pragma unroll
            for (int r = 0; r < 4; r++) acc_s[kc][r] = 0.f;
#pragma unroll
        for (int ks = 0; ks < 3; ks++) {
#pragma unroll
            for (int kc = 0; kc < 4; kc++) {
                s16x8 kh = *(const s16x8*)&K_hi[kc * 16 + li][ks * 32 + g * 8];
                s16x8 kl = *(const s16x8*)&K_lo[kc * 16 + li][ks * 32 + g * 8];
                acc_s[kc] = __builtin_amdgcn_mfma_f32_16x16x32_bf16(q_hi[ks], kh, acc_s[kc], 0, 0, 0);
                acc_s[kc] = __builtin_amdgcn_mfma_f32_16x16x32_bf16(q_lo[ks], kh, acc_s[kc], 0, 0, 0);
                acc_s[kc] = __builtin_amdgcn_mfma_f32_16x16x32_bf16(q_hi[ks], kl, acc_s[kc], 0, 0, 0);
            }
        }
#pragma unroll
        for (int kc = 0; kc < 4; kc++)
#pragma unroll
            for (int r = 0; r < 4; r++) acc_s[kc][r] *= scale;
        if (kt == qt) {
#pragma unroll
            for (int kc = 0; kc < 4; kc++) {
                int key = kt * 64 + kc * 16 + li;
#pragma unroll
                for (int r = 0; r < 4; r++) {
                    int qr = qt * 64 + w * 16 + g * 4 + r;
                    if (key > qr) acc_s[kc][r] = -1e30f;
                }
            }
        }
        float tm[4];
#pragma unroll
        for (int r = 0; r < 4; r++)
            tm[r] = fmaxf(fmaxf(acc_s[0][r], acc_s[1][r]), fmaxf(acc_s[2][r], acc_s[3][r]));
#pragma unroll
        for (int off = 1; off < 16; off <<= 1)
#pragma unroll
            for (int r = 0; r < 4; r++) tm[r] = fmaxf(tm[r], __shfl_xor(tm[r], off));
        float alpha[4];
#pragma unroll
        for (int r = 0; r < 4; r++) {
            float mn = fmaxf(m4[r], tm[r]);
            alpha[r] = __expf(m4[r] - mn);
            m4[r] = mn;
        }
        float rs[4] = {0.f, 0.f, 0.f, 0.f};
#pragma unroll
        for (int kc = 0; kc < 4; kc++)
#pragma unroll
            for (int r = 0; r < 4; r++) {
                float p = __expf(acc_s[kc][r] - m4[r]);
                rs[r] += p;
                short hh = f2bf(p);
                P_hi[w][g * 4 + r][kc * 16 + li] = hh;
                P_lo[w][g * 4 + r][kc * 16 + li] = f2bf(p - bf2f(hh));
            }
#pragma unroll
        for (int off = 1; off < 16; off <<= 1)
#pragma unroll
            for (int r = 0; r < 4; r++) rs[r] += __shfl_xor(rs[r], off);
#pragma unroll
        for (int r = 0; r < 4; r++) l4[r] = l4[r] * alpha[r] + rs[r];
#pragma unroll
        for (int nc = 0; nc < 4; nc++)
#pragma unroll
            for (int r = 0; r < 4; r++) acc_o[nc][r] *= alpha[r];
#pragma unroll
        for (int ks = 0; ks < 2; ks++) {
            s16x8 ph = *(const s16x8*)&P_hi[w][li][ks * 32 + g * 8];
            s16x8 pl = *(const s16x8*)&P_lo[w][li][ks * 32 + g * 8];
#pragma unroll
            for (int nc = 0; nc < 4; nc++) {
                s16x8 vh = *(const s16x8*)&Vt_hi[nc * 16 + li][ks * 32 + g * 8];
                s16x8 vl = *(const s16x8*)&Vt_lo[nc * 16 + li][ks * 32 + g * 8];
                acc_o[nc] = __builtin_amdgcn_mfma_f32_16x16x32_bf16(ph, vh, acc_o[nc], 0, 0, 0);
                acc_o[nc] = __builtin_amdgcn_mfma_f32_16x16x32_bf16(pl, vh, acc_o[nc], 0, 0, 0);
                acc_o[nc] = __builtin_amdgcn_mfma_f32_16x16x32_bf16(ph, vl, acc_o[nc], 0, 0, 0);
            }
        }
        __syncthreads();
    }
    float inv[4];
#pragma unroll
    for (int r = 0; r < 4; r++) inv[r] = 1.f / l4[r];
#pragma unroll
    for (int nc = 0; nc < 4; nc++)
#pragma unroll
        for (int r = 0; r < 4; r++) {
            float o = acc_o[nc][r] * inv[r];
            size_t idx = (size_t)(qt * 64 + w * 16 + g * 4 + r) * 1024 + h * VD + nc * 16 + li;
            short hh = f2bf(o);
            obh[idx] = hh;
            obl[idx] = f2bf(o - bf2f(hh));
        }
}

// ---------------- routing ----------------
__global__ void routing_kernel(const float* __restrict__ h2, const float* __restrict__ gate_w,
                               const float* __restrict__ gate_bias, int* __restrict__ topidx,
                               float* __restrict__ topw) {
    int t = blockIdx.x;
    float acc[8] = {0.f, 0.f, 0.f, 0.f, 0.f, 0.f, 0.f, 0.f};
    for (int i = threadIdx.x; i < HDIM; i += blockDim.x) {
        float hv = h2[(size_t)t * HDIM + i];
        const float* g = gate_w + (size_t)i * 8;
#pragma unroll
        for (int e = 0; e < 8; e++) acc[e] = fmaf(hv, g[e], acc[e]);
    }
    __shared__ float logits[8];
    for (int e = 0; e < 8; e++) {
        float s = block_sum(acc[e]);
        if (threadIdx.x == 0) logits[e] = s;
    }
    __syncthreads();
    if (threadIdx.x == 0) {
        float sig[8], sc[8];
        for (int e = 0; e < 8; e++) {
            sig[e] = 1.f / (1.f + expf(-logits[e]));
            sc[e] = sig[e] + gate_bias[e];
        }
        int i0 = 0;
        for (int e = 1; e < 8; e++) if (sc[e] > sc[i0]) i0 = e;
        int i1 = -1;
        for (int e = 0; e < 8; e++) if (e != i0 && (i1 < 0 || sc[e] > sc[i1])) i1 = e;
        float w0 = sig[i0], w1 = sig[i1], s = w0 + w1 + 1e-20f;
        topidx[t * 2 + 0] = i0; topidx[t * 2 + 1] = i1;
        topw[t * 2 + 0] = w0 / s; topw[t * 2 + 1] = w1 / s;
    }
}

// ---------------- counting sort + tile map ----------------
__global__ void sort_kernel(const int* __restrict__ topidx, int* __restrict__ sorted_t,
                            int* __restrict__ slotpos, int4* __restrict__ tilemap) {
    __shared__ int counts[8], offs[9];
    int wid = threadIdx.x >> 6, lane = threadIdx.x & 63;
    int cnt = 0;
    for (int base = 0; base < 2 * T_; base += 64) {
        int e = topidx[base + lane];
        unsigned long long m = __ballot(e == wid);
        cnt += __popcll(m);
    }
    if (lane == 0) counts[wid] = cnt;
    __syncthreads();
    if (threadIdx.x == 0) {
        offs[0] = 0;
        for (int e = 0; e < 8; e++) offs[e + 1] = offs[e] + counts[e];
    }
    __syncthreads();
    int pos = offs[wid];
    for (int base = 0; base < 2 * T_; base += 64) {
        int sl = base + lane;
        int e = topidx[sl];
        bool match = (e == wid);
        unsigned long long m = __ballot(match);
        if (match) {
            int before = __popcll(m & ((1ull << lane) - 1ull));
            int pp = pos + before;
            sorted_t[pp] = sl >> 1;
            slotpos[sl] = pp;
        }
        pos += __popcll(m);
    }
    __syncthreads();
    if (threadIdx.x == 0) {
        int nt = 0;
        for (int e = 0; e < 8; e++) {
            int c = counts[e], o = offs[e];
            for (int r = 0; r < c; r += 128) {
                tilemap[nt] = make_int4(e, o + r, min(128, c - r), 0);
                nt++;
            }
        }
        for (int i = nt; i < MAXTILES; i++) tilemap[i] = make_int4(0, 0, 0, 0);
    }
}

// ---------------- gather h2 rows (f32, for MoE) ----------------
__global__ void gather_kernel(const float* __restrict__ h2, const int* __restrict__ sorted_t,
                              float* __restrict__ gout) {
    int pp = blockIdx.x;
    int t = sorted_t[pp];
    const float4* src = (const float4*)(h2 + (size_t)t * HDIM);
    float4* dst = (float4*)(gout + (size_t)pp * HDIM);
    for (int i = threadIdx.x; i < HDIM / 4; i += blockDim.x) dst[i] = src[i];
}

// ---------------- elementwise ----------------
__global__ void silu_mul_kernel(float* __restrict__ g, const float* __restrict__ u, int n) {
    int stride = gridDim.x * blockDim.x;
    for (int i = blockIdx.x * blockDim.x + threadIdx.x; i < n; i += stride) {
        float x = g[i];
        g[i] = (x / (1.f + expf(-x))) * u[i];
    }
}

__global__ void silu_mul_bf16_kernel(const float* __restrict__ g, const float* __restrict__ u,
                                     short* __restrict__ outh, int n) {
    int stride = gridDim.x * blockDim.x;
    for (int i = blockIdx.x * blockDim.x + threadIdx.x; i < n; i += stride) {
        float x = g[i];
        outh[i] = f2bf((x / (1.f + expf(-x))) * u[i]);
    }
}

__global__ void add_inplace_kernel(float* __restrict__ x, const float* __restrict__ y, int n) {
    int stride = gridDim.x * blockDim.x;
    for (int i = blockIdx.x * blockDim.x + threadIdx.x; i < n; i += stride) x[i] += y[i];
}

// ---------------- final combine -> f32 out ----------------
__global__ void final_kernel(const float* __restrict__ resid, const float* __restrict__ sho,
                             const float* __restrict__ md, const int* __restrict__ slotpos,
                             const float* __restrict__ topw, float* __restrict__ out) {
    int t = blockIdx.x;
    int p0 = slotpos[t * 2 + 0], p1 = slotpos[t * 2 + 1];
    float w0 = topw[t * 2 + 0] * 2.5f, w1 = topw[t * 2 + 1] * 2.5f;
    for (int c = threadIdx.x; c < HDIM; c += blockDim.x) {
        float v = resid[(size_t)t * HDIM + c] + sho[(size_t)t * HDIM + c]
                + w0 * md[(size_t)p0 * HDIM + c] + w1 * md[(size_t)p1 * HDIM + c];
        out[(size_t)t * HDIM + c] = v;
    }
}

// ---------------- launcher ----------------
extern "C" void kernel_launch(void* const* d_in, const int* in_sizes, int n_in,
                              void* d_out, int out_size, void* d_ws, size_t ws_size,
                              hipStream_t stream) {
    (void)in_sizes; (void)n_in; (void)out_size; (void)ws_size;
    const int*   input_ids = (const int*)d_in[0];
    const int*   positions = (const int*)d_in[1];
    const float* prev      = (const float*)d_in[2];
    const float* embed     = (const float*)d_in[3];
    const float* enorm_w   = (const float*)d_in[4];
    const float* hnorm_w   = (const float*)d_in[5];
    const float* eh_proj_w = (const float*)d_in[6];
    const float* in_ln_w   = (const float*)d_in[7];
    const float* post_ln_w = (const float*)d_in[8];
    const float* q_a_w     = (const float*)d_in[9];
    const float* q_a_ln_w  = (const float*)d_in[10];
    const float* q_b_w     = (const float*)d_in[11];
    const float* kv_a_w    = (const float*)d_in[12];
    const float* kv_a_ln_w = (const float*)d_in[13];
    const float* kv_b_w    = (const float*)d_in[14];
    const float* o_w       = (const float*)d_in[15];
    const float* gate_w    = (const float*)d_in[16];
    const float* gate_bias = (const float*)d_in[17];
    const float* exp_g     = (const float*)d_in[18];
    const float* exp_u     = (const float*)d_in[19];
    const float* exp_d     = (const float*)d_in[20];
    const float* sh_g      = (const float*)d_in[21];
    const float* sh_u      = (const float*)d_in[22];
    const float* sh_d      = (const float*)d_in[23];
    float* out = (float*)d_out;

    float* ws = (float*)d_ws;
    short* catH  = (short*)(ws + OF_CATH);
    short* catL  = (short*)(ws + OF_CATL);
    float* gath  = ws + OF_GATH;
    float* x0    = ws + OF_X0;
    float* h2    = ws + OF_H2;
    short* hH    = (short*)(ws + OF_HH);
    short* hL    = (short*)(ws + OF_HL);
    float* sho   = ws + OF_SHO;
    float* qraw  = ws + OF_QRAW;
    float* qbuf  = ws + OF_QBUF;
    float* kva   = ws + OF_KVA;
    float* kvbuf = ws + OF_KVBUF;
    float* md    = ws + OF_MD;
    short* qaH   = (short*)(ws + OF_QAH);
    short* qaL   = (short*)(ws + OF_QAL);
    short* kvcnH = (short*)(ws + OF_KVCNH);
    short* kvcnL = (short*)(ws + OF_KVCNL);
    short* qfH   = (short*)(ws + OF_QFH);
    short* qfL   = (short*)(ws + OF_QFL);
    short* kfH   = (short*)(ws + OF_KFH);
    short* kfL   = (short*)(ws + OF_KFL);
    short* vbH   = (short*)(ws + OF_VBH);
    short* vbL   = (short*)(ws + OF_VBL);
    float* mg    = ws + OF_MG;
    float* mu    = ws + OF_MU;
    short* obH   = (short*)(ws + OF_OBH);
    short* obL   = (short*)(ws + OF_OBL);
    float* att   = ws + OF_ATT;
    float* sg    = ws + OF_SG;
    float* su    = ws + OF_SU;
    short* h2bf  = (short*)(ws + OF_H2BF);
    short* sgact = (short*)(ws + OF_SGACT);
    int*   ri       = (int*)(ws + OF_ROUT);
    int*   topidx   = ri;
    int*   sorted_t = ri + 2048;
    int*   slotpos  = ri + 4096;
    int4*  tilemap  = (int4*)(ri + 6144);
    float* topw     = (float*)(ri + 6144 + 4 * MAXTILES);
    short* ehTH  = (short*)(ws + OF_EHTH);
    short* ehTL  = (short*)(ws + OF_EHTL);
    short* qaTH  = (short*)(ws + OF_QATH);
    short* qaTL  = (short*)(ws + OF_QATL);
    short* qbTH  = (short*)(ws + OF_QBTH);
    short* qbTL  = (short*)(ws + OF_QBTL);
    short* kvaTH = (short*)(ws + OF_KVATH);
    short* kvaTL = (short*)(ws + OF_KVATL);
    short* kvbTH = (short*)(ws + OF_KVBTH);
    short* kvbTL = (short*)(ws + OF_KVBTL);
    short* owTH  = (short*)(ws + OF_OWTH);
    short* owTL  = (short*)(ws + OF_OWTL);
    short* shgT  = (short*)(ws + OF_SHGT);
    short* shuT  = (short*)(ws + OF_SHUT);
    short* shdT  = (short*)(ws + OF_SHDT);

    dim3 blk(256);

    // 0. weight transpose+split (per launch; weights are const inputs)
    transpose_split_kernel<<<dim3(4096 / 64, 2048 / 64), blk, 0, stream>>>(eh_proj_w, ehTH, ehTL, 4096, 2048, 1);
    transpose_split_kernel<<<dim3(2048 / 64, 512 / 64), blk, 0, stream>>>(q_a_w, qaTH, qaTL, 2048, 512, 1);
    transpose_split_kernel<<<dim3(512 / 64, 1536 / 64), blk, 0, stream>>>(q_b_w, qbTH, qbTL, 512, 1536, 1);
    transpose_split_kernel<<<dim3(2048 / 64, 320 / 64), blk, 0, stream>>>(kv_a_w, kvaTH, kvaTL, 2048, 288, 1);
    transpose_split_kernel<<<dim3(256 / 64, 2048 / 64), blk, 0, stream>>>(kv_b_w, kvbTH, kvbTL, 256, 2048, 1);
    transpose_split_kernel<<<dim3(1024 / 64, 2048 / 64), blk, 0, stream>>>(o_w, owTH, owTL, 1024, 2048, 1);
    transpose_split_kernel<<<dim3(2048 / 64, 1024 / 64), blk, 0, stream>>>(sh_g, shgT, nullptr, 2048, 1024, 0);
    transpose_split_kernel<<<dim3(2048 / 64, 1024 / 64), blk, 0, stream>>>(sh_u, shuT, nullptr, 2048, 1024, 0);
    transpose_split_kernel<<<dim3(1024 / 64, 2048 / 64), blk, 0, stream>>>(sh_d, shdT, nullptr, 1024, 2048, 0);

    // 1. embed + rmsnorm + concat -> split planes
    embed_cat_kernel<<<T_, blk, 0, stream>>>(input_ids, embed, enorm_w, prev, hnorm_w, catH, catL);
    // 2. x0 = cat @ eh_proj
    gemm_planes<true><<<dim3(32, 8), blk, 0, stream>>>(catH, catL, ehTH, ehTL, x0, T_, 2048, 4096);
    // 3. h = rmsnorm(x0) -> planes
    rmsnorm_kernel<<<T_, blk, 0, stream>>>(x0, 2048, 2048, in_ln_w, nullptr, hH, hL, 2048);
    // 4. q_a
    gemm_planes<true><<<dim3(8, 8), blk, 0, stream>>>(hH, hL, qaTH, qaTL, qraw, T_, 512, 2048);
    rmsnorm_kernel<<<T_, blk, 0, stream>>>(qraw, 512, 512, q_a_ln_w, nullptr, qaH, qaL, 512);
    // 5. q = qa @ q_b
    gemm_planes<true><<<dim3(24, 8), blk, 0, stream>>>(qaH, qaL, qbTH, qbTL, qbuf, T_, 1536, 512);
    // 6. kva = h @ kv_a
    gemm_planes<true><<<dim3(5, 8), blk, 0, stream>>>(hH, hL, kvaTH, kvaTL, kva, T_, 288, 2048);
    // 7. kvcn
    rmsnorm_kernel<<<T_, blk, 0, stream>>>(kva, 288, 256, kv_a_ln_w, nullptr, kvcnH, kvcnL, 256);
    // 8. kv = kvcn @ kv_b
    gemm_planes<true><<<dim3(32, 8), blk, 0, stream>>>(kvcnH, kvcnL, kvbTH, kvbTL, kvbuf, T_, 2048, 256);
    // 9. rope + planes
    prep_qkv_kernel<<<T_, blk, 0, stream>>>(qbuf, kva, kvbuf, positions, qfH, qfL, kfH, kfL, vbH, vbL);
    // 10. flash attention
    attn_mfma_kernel<<<dim3(T_ / 64, NH), blk, 0, stream>>>(qfH, qfL, kfH, kfL, vbH, vbL, obH, obL);
    // 11. attn_out = ob @ o_w
    gemm_planes<true><<<dim3(32, 8), blk, 0, stream>>>(obH, obL, owTH, owTL, att, T_, 2048, 1024);
    // 12. resid += attn_out
    add_inplace_kernel<<<2048, blk, 0, stream>>>(x0, att, T_ * 2048);
    // 13. h2 = rmsnorm(resid): f32 (routing/gather) + hi plane (shared GEMMs)
    rmsnorm_kernel<<<T_, blk, 0, stream>>>(x0, 2048, 2048, post_ln_w, h2, h2bf, nullptr, 2048);
    // 14. routing
    routing_kernel<<<T_, blk, 0, stream>>>(h2, gate_w, gate_bias, topidx, topw);
    // 15. sort
    sort_kernel<<<1, 512, 0, stream>>>(topidx, sorted_t, slotpos, tilemap);
    // 16. gather
    gather_kernel<<<2 * T_, blk, 0, stream>>>(h2, sorted_t, gath);
    // 17. MoE gate/up
    moe_gemm_bf16<<<dim3(16, MAXTILES), blk, 0, stream>>>(gath, exp_g, mg, tilemap, 2048, 1024);
    moe_gemm_bf16<<<dim3(16, MAXTILES), blk, 0, stream>>>(gath, exp_u, mu, tilemap, 2048, 1024);
    // 18. silu
    silu_mul_kernel<<<2048, blk, 0, stream>>>(mg, mu, 2048 * 1024);
    // 19. MoE down
    moe_gemm_bf16<<<dim3(32, MAXTILES), blk, 0, stream>>>(mg, exp_d, md, tilemap, 1024, 2048);
    // 20. shared MLP via planes
    gemm_planes<false><<<dim3(16, 8), blk, 0, stream>>>(h2bf, h2bf, shgT, shgT, sg, T_, 1024, 2048);
    gemm_planes<false><<<dim3(16, 8), blk, 0, stream>>>(h2bf, h2bf, shuT, shuT, su, T_, 1024, 2048);
    silu_mul_bf16_kernel<<<1024, blk, 0, stream>>>(sg, su, sgact, T_ * 1024);
    gemm_planes<false><<<dim3(32, 8), blk, 0, stream>>>(sgact, sgact, shdT, shdT, sho, T_, 2048, 1024);
    // 21. final combine
    final_kernel<<<T_, blk, 0, stream>>>(x0, sho, md, slotpos, topw, out);
}